// Round 2
// baseline (1845.903 us; speedup 1.0000x reference)
//
#include <hip/hip_runtime.h>
#include <hip/hip_bf16.h>

#define N_NODES 100000
#define N_EDGES 400000
#define IN_DIM  69
#define KP1     96      // IN_DIM padded to multiple of 32
#define HID     256
#define NG      4096

typedef __attribute__((ext_vector_type(8))) short bf16x8;
typedef __attribute__((ext_vector_type(4))) float f32x4;
typedef unsigned short u16;
typedef unsigned int   u32;

__device__ __forceinline__ float b2f(u16 v) {
    u32 x = ((u32)v) << 16;
    return __builtin_bit_cast(float, x);
}
__device__ __forceinline__ u16 f2b(float f) {
    u32 x = __builtin_bit_cast(u32, f);
    u32 r = (x + 0x7FFF + ((x >> 16) & 1)) >> 16;   // RNE
    return (u16)r;
}

// ---- degree count: deg[dst[e]] += 1 ----
__global__ void k_deg(const int* __restrict__ dst, float* __restrict__ deg) {
    int e = blockIdx.x * blockDim.x + threadIdx.x;
    if (e < N_EDGES) unsafeAtomicAdd(&deg[dst[e]], 1.0f);
}

// ---- dinv = rsqrt(deg+1); also per-graph node counts ----
__global__ void k_dinv_cnt(const float* __restrict__ deg, float* __restrict__ dinv,
                           const int* __restrict__ batch, float* __restrict__ cnt) {
    int n = blockIdx.x * blockDim.x + threadIdx.x;
    if (n < N_NODES) {
        dinv[n] = rsqrtf(deg[n] + 1.0f);
        unsafeAtomicAdd(&cnt[batch[n]], 1.0f);
    }
}

// ---- transpose W [K x 256] f32 -> Wt [256 x KP] bf16, zero-padded ----
__global__ void k_transpose_w(const float* __restrict__ W, u16* __restrict__ Wt, int K, int KP) {
    int k = blockIdx.x;       // 0..KP-1
    int n = threadIdx.x;      // 0..255
    Wt[(size_t)n * KP + k] = (k < K) ? f2b(W[(size_t)k * HID + n]) : (u16)0;
}

// ---- pad x [N x 69] f32 -> Xpad [N x 96] bf16 ----
__global__ void k_pad_x(const float* __restrict__ x, u16* __restrict__ xp) {
    int m = blockIdx.x;
    int j = threadIdx.x;
    if (j < KP1) xp[(size_t)m * KP1 + j] = (j < IN_DIM) ? f2b(x[(size_t)m * IN_DIM + j]) : (u16)0;
}

// ---- GEMM: g = dinv[m] * (A @ Wt^T); writes Gout (bf16) and acc (f32, self-loop init) ----
// A: [M x KP] bf16 row-major (KP = 96 or 256), Wt: [256 x KP] bf16 row-major.
__global__ __launch_bounds__(256) void k_gemm(const u16* __restrict__ A, int KP, int M,
                                              const u16* __restrict__ Wt,
                                              const float* __restrict__ dinv,
                                              u16* __restrict__ Gout, float* __restrict__ acc_out) {
    __shared__ __align__(16) u16 As[64 * 40];    // 64 rows x 32 k, stride 40
    __shared__ __align__(16) u16 Bs[256 * 40];   // 256 cols x 32 k, stride 40

    const int tid  = threadIdx.x;
    const int wave = tid >> 6;
    const int lane = tid & 63;
    const int quad = lane >> 4;
    const int lm   = lane & 15;
    const int m0   = blockIdx.x * 64;

    f32x4 acc[4][4] = {};

    const int ar = tid >> 2;          // 0..63 (row for A staging)
    const int ai = (tid & 3) * 8;     // 0,8,16,24 (k-chunk for A staging)

    for (int kt = 0; kt < KP; kt += 32) {
        __syncthreads();
        // stage A tile 64x32
        {
            int m = m0 + ar;
            uint4 v = make_uint4(0, 0, 0, 0);
            if (m < M) v = *(const uint4*)(A + (size_t)m * KP + kt + ai);
            *(uint4*)(As + ar * 40 + ai) = v;
        }
        // stage B tile 256 cols x 32 k (from transposed W: contiguous k)
        #pragma unroll
        for (int p = 0; p < 4; ++p) {
            int n = p * 64 + (tid >> 2);
            uint4 v = *(const uint4*)(Wt + (size_t)n * KP + kt + ai);
            *(uint4*)(Bs + n * 40 + ai) = v;
        }
        __syncthreads();

        bf16x8 af[4], bf[4];
        #pragma unroll
        for (int rt = 0; rt < 4; ++rt)
            af[rt] = *(const bf16x8*)(As + (rt * 16 + lm) * 40 + quad * 8);
        #pragma unroll
        for (int ct = 0; ct < 4; ++ct)
            bf[ct] = *(const bf16x8*)(Bs + (wave * 64 + ct * 16 + lm) * 40 + quad * 8);
        #pragma unroll
        for (int rt = 0; rt < 4; ++rt)
            #pragma unroll
            for (int ct = 0; ct < 4; ++ct)
                acc[rt][ct] = __builtin_amdgcn_mfma_f32_16x16x32_bf16(af[rt], bf[ct], acc[rt][ct], 0, 0, 0);
    }

    // epilogue: C/D layout col=lane&15, row=quad*4+reg
    #pragma unroll
    for (int rt = 0; rt < 4; ++rt) {
        #pragma unroll
        for (int reg = 0; reg < 4; ++reg) {
            int m = m0 + rt * 16 + quad * 4 + reg;
            if (m >= M) continue;
            float dv = dinv[m];
            #pragma unroll
            for (int ct = 0; ct < 4; ++ct) {
                int n = wave * 64 + ct * 16 + lm;
                float g = dv * acc[rt][ct][reg];
                acc_out[(size_t)m * HID + n] = g;      // self-loop init
                Gout[(size_t)m * HID + n]   = f2b(g);
            }
        }
    }
}

// ---- scatter: acc[dst] += g[src], one edge per 256-thread block ----
__global__ void k_scatter(const int* __restrict__ src, const int* __restrict__ dst,
                          const u16* __restrict__ g, float* __restrict__ acc) {
    int e = blockIdx.x;
    int j = threadIdx.x;
    int s = src[e];
    int d = dst[e];
    float v = b2f(g[(size_t)s * HID + j]);
    unsafeAtomicAdd(&acc[(size_t)d * HID + j], v);
}

// ---- epilogue layers 1-3: X' = relu(dinv*acc + b), bf16 out ----
__global__ void k_epi_relu(const float* __restrict__ acc, const float* __restrict__ dinv,
                           const float* __restrict__ bias, u16* __restrict__ Xout) {
    int m = blockIdx.x;
    int j = threadIdx.x;
    float v = dinv[m] * acc[(size_t)m * HID + j] + bias[j];
    v = fmaxf(v, 0.0f);
    Xout[(size_t)m * HID + j] = f2b(v);
}

// ---- epilogue layer 4: h4 = dinv*acc + b4 (no relu); pool into psum ----
__global__ void k_epi_pool(const float* __restrict__ acc, const float* __restrict__ dinv,
                           const float* __restrict__ bias, const int* __restrict__ batch,
                           float* __restrict__ psum) {
    int m = blockIdx.x;
    int j = threadIdx.x;
    float v = dinv[m] * acc[(size_t)m * HID + j] + bias[j];
    unsafeAtomicAdd(&psum[(size_t)batch[m] * HID + j], v);
}

// ---- final: out[g][c] = (psum[g]/max(cnt,1)) @ Wl + bl, f32 out ----
__global__ void k_final(const float* __restrict__ psum, const float* __restrict__ cnt,
                        const float* __restrict__ Wl, const float* __restrict__ bl,
                        float* __restrict__ out) {
    __shared__ float s0[256], s1[256];
    int gph = blockIdx.x;
    int j = threadIdx.x;
    float inv = 1.0f / fmaxf(cnt[gph], 1.0f);
    float p = psum[(size_t)gph * HID + j] * inv;
    s0[j] = p * Wl[j * 2 + 0];
    s1[j] = p * Wl[j * 2 + 1];
    __syncthreads();
    for (int off = 128; off >= 1; off >>= 1) {
        if (j < off) { s0[j] += s0[j + off]; s1[j] += s1[j + off]; }
        __syncthreads();
    }
    if (j == 0) {
        out[gph * 2 + 0] = s0[0] + bl[0];
        out[gph * 2 + 1] = s1[0] + bl[1];
    }
}

extern "C" void kernel_launch(void* const* d_in, const int* in_sizes, int n_in,
                              void* d_out, int out_size, void* d_ws, size_t ws_size,
                              hipStream_t stream) {
    const float* x   = (const float*)d_in[0];
    const int* ei    = (const int*)d_in[1];
    const int* src   = ei;
    const int* dst   = ei + N_EDGES;
    const int* batch = (const int*)d_in[2];
    const float* W1 = (const float*)d_in[3];  const float* b1 = (const float*)d_in[4];
    const float* W2 = (const float*)d_in[5];  const float* b2 = (const float*)d_in[6];
    const float* W3 = (const float*)d_in[7];  const float* b3 = (const float*)d_in[8];
    const float* W4 = (const float*)d_in[9];  const float* b4 = (const float*)d_in[10];
    const float* Wl = (const float*)d_in[11]; const float* bl = (const float*)d_in[12];
    float* out = (float*)d_out;

    // ---- workspace layout ----
    char* p = (char*)d_ws;
    auto take = [&](size_t bytes) { char* r = p; p += (bytes + 255) & ~(size_t)255; return r; };
    // contiguous zero block: deg | cnt | psum
    size_t zbytes = (size_t)(N_NODES + NG + NG * HID) * sizeof(float);
    float* deg  = (float*)take(zbytes);
    float* cnt  = deg + N_NODES;
    float* psum = cnt + NG;
    float* dinv = (float*)take((size_t)N_NODES * sizeof(float));
    u16* Wt1 = (u16*)take((size_t)HID * KP1 * 2);
    u16* Wt2 = (u16*)take((size_t)HID * HID * 2);
    u16* Wt3 = (u16*)take((size_t)HID * HID * 2);
    u16* Wt4 = (u16*)take((size_t)HID * HID * 2);
    float* acc = (float*)take((size_t)N_NODES * HID * sizeof(float));
    u16* Gbuf  = (u16*)take((size_t)N_NODES * HID * 2);
    u16* Xbuf  = (u16*)take((size_t)N_NODES * HID * 2);
    u16* Xpad  = Xbuf;   // alias: layer-1 padded input dead before Xbuf first written

    hipMemsetAsync(deg, 0, zbytes, stream);

    k_deg<<<(N_EDGES + 255) / 256, 256, 0, stream>>>(dst, deg);
    k_dinv_cnt<<<(N_NODES + 255) / 256, 256, 0, stream>>>(deg, dinv, batch, cnt);

    k_transpose_w<<<KP1, 256, 0, stream>>>(W1, Wt1, IN_DIM, KP1);
    k_transpose_w<<<HID, 256, 0, stream>>>(W2, Wt2, HID, HID);
    k_transpose_w<<<HID, 256, 0, stream>>>(W3, Wt3, HID, HID);
    k_transpose_w<<<HID, 256, 0, stream>>>(W4, Wt4, HID, HID);
    k_pad_x<<<N_NODES, 128, 0, stream>>>(x, Xpad);

    const int gemm_grid = (N_NODES + 63) / 64;

    // layer 1
    k_gemm<<<gemm_grid, 256, 0, stream>>>(Xpad, KP1, N_NODES, Wt1, dinv, Gbuf, acc);
    k_scatter<<<N_EDGES, 256, 0, stream>>>(src, dst, Gbuf, acc);
    k_epi_relu<<<N_NODES, 256, 0, stream>>>(acc, dinv, b1, Xbuf);
    // layer 2
    k_gemm<<<gemm_grid, 256, 0, stream>>>(Xbuf, HID, N_NODES, Wt2, dinv, Gbuf, acc);
    k_scatter<<<N_EDGES, 256, 0, stream>>>(src, dst, Gbuf, acc);
    k_epi_relu<<<N_NODES, 256, 0, stream>>>(acc, dinv, b2, Xbuf);
    // layer 3
    k_gemm<<<gemm_grid, 256, 0, stream>>>(Xbuf, HID, N_NODES, Wt3, dinv, Gbuf, acc);
    k_scatter<<<N_EDGES, 256, 0, stream>>>(src, dst, Gbuf, acc);
    k_epi_relu<<<N_NODES, 256, 0, stream>>>(acc, dinv, b3, Xbuf);
    // layer 4 + pooling
    k_gemm<<<gemm_grid, 256, 0, stream>>>(Xbuf, HID, N_NODES, Wt4, dinv, Gbuf, acc);
    k_scatter<<<N_EDGES, 256, 0, stream>>>(src, dst, Gbuf, acc);
    k_epi_pool<<<N_NODES, 256, 0, stream>>>(acc, dinv, b4, batch, psum);

    k_final<<<NG, 256, 0, stream>>>(psum, cnt, Wl, bl, out);
}

// Round 3
// 861.322 us; speedup vs baseline: 2.1431x; 2.1431x over previous
//
#include <hip/hip_runtime.h>
#include <hip/hip_bf16.h>

#define N_NODES 100000
#define N_EDGES 400000
#define IN_DIM  69
#define KP1     96      // IN_DIM padded to multiple of 32
#define HID     256
#define NG      4096
#define SCAN_B  391     // ceil(N_NODES / 256)

typedef __attribute__((ext_vector_type(8))) short bf16x8;
typedef __attribute__((ext_vector_type(4))) float f32x4;
typedef unsigned short u16;
typedef unsigned int   u32;

__device__ __forceinline__ float b2f(u16 v) {
    u32 x = ((u32)v) << 16;
    return __builtin_bit_cast(float, x);
}
__device__ __forceinline__ u16 f2b(float f) {
    u32 x = __builtin_bit_cast(u32, f);
    u32 r = (x + 0x7FFF + ((x >> 16) & 1)) >> 16;   // RNE
    return (u16)r;
}

// ---- in-degree count (int) ----
__global__ void k_deg(const int* __restrict__ dst, int* __restrict__ deg) {
    int e = blockIdx.x * blockDim.x + threadIdx.x;
    if (e < N_EDGES) atomicAdd(&deg[dst[e]], 1);
}

// ---- dinv = rsqrt(deg+1); per-graph node counts ----
__global__ void k_dinv_cnt(const int* __restrict__ deg, float* __restrict__ dinv,
                           const int* __restrict__ batch, float* __restrict__ cnt) {
    int n = blockIdx.x * blockDim.x + threadIdx.x;
    if (n < N_NODES) {
        dinv[n] = rsqrtf((float)deg[n] + 1.0f);
        unsafeAtomicAdd(&cnt[batch[n]], 1.0f);
    }
}

// ---- two-level exclusive scan of deg -> rowptr ----
__global__ void k_scan_local(const int* __restrict__ deg, int* __restrict__ rowptr,
                             int* __restrict__ bsum) {
    __shared__ int s[256];
    int tid = threadIdx.x;
    int i = blockIdx.x * 256 + tid;
    int v = (i < N_NODES) ? deg[i] : 0;
    s[tid] = v;
    __syncthreads();
    #pragma unroll
    for (int off = 1; off < 256; off <<= 1) {
        int t = 0;
        if (tid >= off) t = s[tid - off];
        __syncthreads();
        if (tid >= off) s[tid] += t;
        __syncthreads();
    }
    if (i < N_NODES) rowptr[i] = s[tid] - v;          // exclusive
    if (tid == 255) bsum[blockIdx.x] = s[255];        // block total
}

__global__ void k_scan_bsum(int* __restrict__ bsum, int* __restrict__ boff) {
    __shared__ int s[512];
    int tid = threadIdx.x;
    int v = (tid < SCAN_B) ? bsum[tid] : 0;
    s[tid] = v;
    __syncthreads();
    #pragma unroll
    for (int off = 1; off < 512; off <<= 1) {
        int t = 0;
        if (tid >= off) t = s[tid - off];
        __syncthreads();
        if (tid >= off) s[tid] += t;
        __syncthreads();
    }
    if (tid < SCAN_B) boff[tid] = s[tid] - v;         // exclusive
}

__global__ void k_scan_add(int* __restrict__ rowptr, const int* __restrict__ boff) {
    int i = blockIdx.x * 256 + threadIdx.x;
    if (i < N_NODES) rowptr[i] += boff[blockIdx.x];
    if (i == 0) rowptr[N_NODES] = N_EDGES;
}

// ---- CSR fill: col[rowptr[d] + fill[d]++] = src[e] ----
__global__ void k_fill(const int* __restrict__ src, const int* __restrict__ dst,
                       const int* __restrict__ rowptr, int* __restrict__ fill,
                       int* __restrict__ col) {
    int e = blockIdx.x * blockDim.x + threadIdx.x;
    if (e < N_EDGES) {
        int d = dst[e];
        int pos = rowptr[d] + atomicAdd(&fill[d], 1);
        col[pos] = src[e];
    }
}

// ---- transpose W [K x 256] f32 -> Wt [256 x KP] bf16, zero-padded ----
__global__ void k_transpose_w(const float* __restrict__ W, u16* __restrict__ Wt, int K, int KP) {
    int k = blockIdx.x;
    int n = threadIdx.x;
    Wt[(size_t)n * KP + k] = (k < K) ? f2b(W[(size_t)k * HID + n]) : (u16)0;
}

// ---- pad x [N x 69] f32 -> Xpad [N x 96] bf16 ----
__global__ void k_pad_x(const float* __restrict__ x, u16* __restrict__ xp) {
    int m = blockIdx.x;
    int j = threadIdx.x;
    if (j < KP1) xp[(size_t)m * KP1 + j] = (j < IN_DIM) ? f2b(x[(size_t)m * IN_DIM + j]) : (u16)0;
}

// ---- GEMM: g = dinv[m] * (A @ Wt^T), bf16 out ----
__global__ __launch_bounds__(256) void k_gemm(const u16* __restrict__ A, int KP, int M,
                                              const u16* __restrict__ Wt,
                                              const float* __restrict__ dinv,
                                              u16* __restrict__ Gout) {
    __shared__ __align__(16) u16 As[64 * 40];
    __shared__ __align__(16) u16 Bs[256 * 40];

    const int tid  = threadIdx.x;
    const int wave = tid >> 6;
    const int lane = tid & 63;
    const int quad = lane >> 4;
    const int lm   = lane & 15;
    const int m0   = blockIdx.x * 64;

    f32x4 acc[4][4] = {};

    const int ar = tid >> 2;
    const int ai = (tid & 3) * 8;

    for (int kt = 0; kt < KP; kt += 32) {
        __syncthreads();
        {
            int m = m0 + ar;
            uint4 v = make_uint4(0, 0, 0, 0);
            if (m < M) v = *(const uint4*)(A + (size_t)m * KP + kt + ai);
            *(uint4*)(As + ar * 40 + ai) = v;
        }
        #pragma unroll
        for (int p = 0; p < 4; ++p) {
            int n = p * 64 + (tid >> 2);
            uint4 v = *(const uint4*)(Wt + (size_t)n * KP + kt + ai);
            *(uint4*)(Bs + n * 40 + ai) = v;
        }
        __syncthreads();

        bf16x8 af[4], bfr[4];
        #pragma unroll
        for (int rt = 0; rt < 4; ++rt)
            af[rt] = *(const bf16x8*)(As + (rt * 16 + lm) * 40 + quad * 8);
        #pragma unroll
        for (int ct = 0; ct < 4; ++ct)
            bfr[ct] = *(const bf16x8*)(Bs + (wave * 64 + ct * 16 + lm) * 40 + quad * 8);
        #pragma unroll
        for (int rt = 0; rt < 4; ++rt)
            #pragma unroll
            for (int ct = 0; ct < 4; ++ct)
                acc[rt][ct] = __builtin_amdgcn_mfma_f32_16x16x32_bf16(af[rt], bfr[ct], acc[rt][ct], 0, 0, 0);
    }

    #pragma unroll
    for (int rt = 0; rt < 4; ++rt) {
        #pragma unroll
        for (int reg = 0; reg < 4; ++reg) {
            int m = m0 + rt * 16 + quad * 4 + reg;
            if (m >= M) continue;
            float dv = dinv[m];
            #pragma unroll
            for (int ct = 0; ct < 4; ++ct) {
                int n = wave * 64 + ct * 16 + lm;
                Gout[(size_t)m * HID + n] = f2b(dv * acc[rt][ct][reg]);
            }
        }
    }
}

// ---- aggregate: out[d] = dinv[d]*(g[d] + sum_{s->d} g[s]) + b ; relu->bf16 or pool ----
// one wave per node, lane owns 4 dims (8B bf16x4 loads -> 512B/wave per row)
template<int MODE>   // 0: relu -> Xout bf16 ; 1: pool -> psum f32 atomics
__global__ __launch_bounds__(256) void k_agg(const int* __restrict__ rowptr,
                                             const int* __restrict__ col,
                                             const u16* __restrict__ g,
                                             const float* __restrict__ dinv,
                                             const float* __restrict__ bias,
                                             const int* __restrict__ batch,
                                             u16* __restrict__ Xout,
                                             float* __restrict__ psum) {
    int node = blockIdx.x * 4 + (threadIdx.x >> 6);
    if (node >= N_NODES) return;
    int lane = threadIdx.x & 63;
    int j = lane * 4;

    float a0, a1, a2, a3;
    {   // self-loop term
        uint2 v = *(const uint2*)(g + (size_t)node * HID + j);
        a0 = b2f((u16)(v.x & 0xffff)); a1 = b2f((u16)(v.x >> 16));
        a2 = b2f((u16)(v.y & 0xffff)); a3 = b2f((u16)(v.y >> 16));
    }
    int beg = rowptr[node], end = rowptr[node + 1];
    for (int e = beg; e < end; ++e) {
        int s = col[e];
        uint2 v = *(const uint2*)(g + (size_t)s * HID + j);
        a0 += b2f((u16)(v.x & 0xffff)); a1 += b2f((u16)(v.x >> 16));
        a2 += b2f((u16)(v.y & 0xffff)); a3 += b2f((u16)(v.y >> 16));
    }
    float dv = dinv[node];
    float4 bb = *(const float4*)(bias + j);
    a0 = a0 * dv + bb.x; a1 = a1 * dv + bb.y;
    a2 = a2 * dv + bb.z; a3 = a3 * dv + bb.w;

    if (MODE == 0) {
        a0 = fmaxf(a0, 0.0f); a1 = fmaxf(a1, 0.0f);
        a2 = fmaxf(a2, 0.0f); a3 = fmaxf(a3, 0.0f);
        uint2 o;
        o.x = (u32)f2b(a0) | ((u32)f2b(a1) << 16);
        o.y = (u32)f2b(a2) | ((u32)f2b(a3) << 16);
        *(uint2*)(Xout + (size_t)node * HID + j) = o;
    } else {
        float* pp = psum + (size_t)batch[node] * HID + j;
        unsafeAtomicAdd(pp + 0, a0);
        unsafeAtomicAdd(pp + 1, a1);
        unsafeAtomicAdd(pp + 2, a2);
        unsafeAtomicAdd(pp + 3, a3);
    }
}

// ---- final: out[g][c] = (psum[g]/max(cnt,1)) @ Wl + bl, f32 out ----
__global__ void k_final(const float* __restrict__ psum, const float* __restrict__ cnt,
                        const float* __restrict__ Wl, const float* __restrict__ bl,
                        float* __restrict__ out) {
    __shared__ float s0[256], s1[256];
    int gph = blockIdx.x;
    int j = threadIdx.x;
    float inv = 1.0f / fmaxf(cnt[gph], 1.0f);
    float p = psum[(size_t)gph * HID + j] * inv;
    s0[j] = p * Wl[j * 2 + 0];
    s1[j] = p * Wl[j * 2 + 1];
    __syncthreads();
    for (int off = 128; off >= 1; off >>= 1) {
        if (j < off) { s0[j] += s0[j + off]; s1[j] += s1[j + off]; }
        __syncthreads();
    }
    if (j == 0) {
        out[gph * 2 + 0] = s0[0] + bl[0];
        out[gph * 2 + 1] = s1[0] + bl[1];
    }
}

extern "C" void kernel_launch(void* const* d_in, const int* in_sizes, int n_in,
                              void* d_out, int out_size, void* d_ws, size_t ws_size,
                              hipStream_t stream) {
    const float* x   = (const float*)d_in[0];
    const int* ei    = (const int*)d_in[1];
    const int* src   = ei;
    const int* dst   = ei + N_EDGES;
    const int* batch = (const int*)d_in[2];
    const float* W1 = (const float*)d_in[3];  const float* b1 = (const float*)d_in[4];
    const float* W2 = (const float*)d_in[5];  const float* b2 = (const float*)d_in[6];
    const float* W3 = (const float*)d_in[7];  const float* b3 = (const float*)d_in[8];
    const float* W4 = (const float*)d_in[9];  const float* b4 = (const float*)d_in[10];
    const float* Wl = (const float*)d_in[11]; const float* bl = (const float*)d_in[12];
    float* out = (float*)d_out;

    // ---- workspace layout ----
    char* p = (char*)d_ws;
    auto take = [&](size_t bytes) { char* r = p; p += (bytes + 255) & ~(size_t)255; return r; };
    // contiguous zero block: deg(int) | fill(int) | cnt(f32) | psum(f32)
    size_t zbytes = (size_t)(N_NODES + N_NODES + NG + NG * HID) * 4;
    int*   deg  = (int*)take(zbytes);
    int*   fill = deg + N_NODES;
    float* cnt  = (float*)(fill + N_NODES);
    float* psum = cnt + NG;
    float* dinv = (float*)take((size_t)N_NODES * sizeof(float));
    int* rowptr = (int*)take((size_t)(N_NODES + 1) * sizeof(int));
    int* col    = (int*)take((size_t)N_EDGES * sizeof(int));
    int* bsum   = (int*)take((size_t)SCAN_B * sizeof(int));
    int* boff   = (int*)take((size_t)SCAN_B * sizeof(int));
    u16* Wt1 = (u16*)take((size_t)HID * KP1 * 2);
    u16* Wt2 = (u16*)take((size_t)HID * HID * 2);
    u16* Wt3 = (u16*)take((size_t)HID * HID * 2);
    u16* Wt4 = (u16*)take((size_t)HID * HID * 2);
    u16* Gbuf = (u16*)take((size_t)N_NODES * HID * 2);
    u16* Xbuf = (u16*)take((size_t)N_NODES * HID * 2);
    u16* Xpad = Xbuf;   // alias: layer-1 padded input dead before Xbuf first written

    hipMemsetAsync(deg, 0, zbytes, stream);

    // CSR build + norms
    k_deg<<<(N_EDGES + 255) / 256, 256, 0, stream>>>(dst, deg);
    k_scan_local<<<SCAN_B, 256, 0, stream>>>(deg, rowptr, bsum);
    k_scan_bsum<<<1, 512, 0, stream>>>(bsum, boff);
    k_scan_add<<<SCAN_B, 256, 0, stream>>>(rowptr, boff);
    k_fill<<<(N_EDGES + 255) / 256, 256, 0, stream>>>(src, dst, rowptr, fill, col);
    k_dinv_cnt<<<(N_NODES + 255) / 256, 256, 0, stream>>>(deg, dinv, batch, cnt);

    k_transpose_w<<<KP1, 256, 0, stream>>>(W1, Wt1, IN_DIM, KP1);
    k_transpose_w<<<HID, 256, 0, stream>>>(W2, Wt2, HID, HID);
    k_transpose_w<<<HID, 256, 0, stream>>>(W3, Wt3, HID, HID);
    k_transpose_w<<<HID, 256, 0, stream>>>(W4, Wt4, HID, HID);
    k_pad_x<<<N_NODES, 128, 0, stream>>>(x, Xpad);

    const int gemm_grid = (N_NODES + 63) / 64;
    const int agg_grid  = (N_NODES + 3) / 4;

    // layer 1
    k_gemm<<<gemm_grid, 256, 0, stream>>>(Xpad, KP1, N_NODES, Wt1, dinv, Gbuf);
    k_agg<0><<<agg_grid, 256, 0, stream>>>(rowptr, col, Gbuf, dinv, b1, batch, Xbuf, psum);
    // layer 2
    k_gemm<<<gemm_grid, 256, 0, stream>>>(Xbuf, HID, N_NODES, Wt2, dinv, Gbuf);
    k_agg<0><<<agg_grid, 256, 0, stream>>>(rowptr, col, Gbuf, dinv, b2, batch, Xbuf, psum);
    // layer 3
    k_gemm<<<gemm_grid, 256, 0, stream>>>(Xbuf, HID, N_NODES, Wt3, dinv, Gbuf);
    k_agg<0><<<agg_grid, 256, 0, stream>>>(rowptr, col, Gbuf, dinv, b3, batch, Xbuf, psum);
    // layer 4 + pooling
    k_gemm<<<gemm_grid, 256, 0, stream>>>(Xbuf, HID, N_NODES, Wt4, dinv, Gbuf);
    k_agg<1><<<agg_grid, 256, 0, stream>>>(rowptr, col, Gbuf, dinv, b4, batch, Xbuf, psum);

    k_final<<<NG, 256, 0, stream>>>(psum, cnt, Wl, bl, out);
}

// Round 4
// 536.315 us; speedup vs baseline: 3.4418x; 1.6060x over previous
//
#include <hip/hip_runtime.h>
#include <hip/hip_bf16.h>

#define N_NODES 100000
#define N_EDGES 400000
#define IN_DIM  69
#define KP1     96      // IN_DIM padded to multiple of 32
#define HID     256
#define NG      4096
#define SCAN_B  391     // ceil(N_NODES / 256)

typedef __attribute__((ext_vector_type(8))) short bf16x8;
typedef __attribute__((ext_vector_type(4))) float f32x4;
typedef unsigned short u16;
typedef unsigned int   u32;

__device__ __forceinline__ float b2f(u16 v) {
    u32 x = ((u32)v) << 16;
    return __builtin_bit_cast(float, x);
}
__device__ __forceinline__ u16 f2b(float f) {
    u32 x = __builtin_bit_cast(u32, f);
    u32 r = (x + 0x7FFF + ((x >> 16) & 1)) >> 16;   // RNE
    return (u16)r;
}
__device__ __forceinline__ float lo16(u32 v) { return b2f((u16)(v & 0xffff)); }
__device__ __forceinline__ float hi16(u32 v) { return b2f((u16)(v >> 16)); }

// ---- in-degree count (int) ----
__global__ void k_deg(const int* __restrict__ dst, int* __restrict__ deg) {
    int e = blockIdx.x * blockDim.x + threadIdx.x;
    if (e < N_EDGES) atomicAdd(&deg[dst[e]], 1);
}

// ---- dinv = rsqrt(deg+1) ----
__global__ void k_dinv(const int* __restrict__ deg, float* __restrict__ dinv) {
    int n = blockIdx.x * blockDim.x + threadIdx.x;
    if (n < N_NODES) dinv[n] = rsqrtf((float)deg[n] + 1.0f);
}

// ---- two-level exclusive scan of deg -> rowptr ----
__global__ void k_scan_local(const int* __restrict__ deg, int* __restrict__ rowptr,
                             int* __restrict__ bsum) {
    __shared__ int s[256];
    int tid = threadIdx.x;
    int i = blockIdx.x * 256 + tid;
    int v = (i < N_NODES) ? deg[i] : 0;
    s[tid] = v;
    __syncthreads();
    #pragma unroll
    for (int off = 1; off < 256; off <<= 1) {
        int t = 0;
        if (tid >= off) t = s[tid - off];
        __syncthreads();
        if (tid >= off) s[tid] += t;
        __syncthreads();
    }
    if (i < N_NODES) rowptr[i] = s[tid] - v;          // exclusive
    if (tid == 255) bsum[blockIdx.x] = s[255];        // block total
}

__global__ void k_scan_bsum(int* __restrict__ bsum, int* __restrict__ boff) {
    __shared__ int s[512];
    int tid = threadIdx.x;
    int v = (tid < SCAN_B) ? bsum[tid] : 0;
    s[tid] = v;
    __syncthreads();
    #pragma unroll
    for (int off = 1; off < 512; off <<= 1) {
        int t = 0;
        if (tid >= off) t = s[tid - off];
        __syncthreads();
        if (tid >= off) s[tid] += t;
        __syncthreads();
    }
    if (tid < SCAN_B) boff[tid] = s[tid] - v;         // exclusive
}

__global__ void k_scan_add(int* __restrict__ rowptr, const int* __restrict__ boff) {
    int i = blockIdx.x * 256 + threadIdx.x;
    if (i < N_NODES) rowptr[i] += boff[blockIdx.x];
    if (i == 0) rowptr[N_NODES] = N_EDGES;
}

// ---- CSR fill: col[rowptr[d] + fill[d]++] = src[e] ----
__global__ void k_fill(const int* __restrict__ src, const int* __restrict__ dst,
                       const int* __restrict__ rowptr, int* __restrict__ fill,
                       int* __restrict__ col) {
    int e = blockIdx.x * blockDim.x + threadIdx.x;
    if (e < N_EDGES) {
        int d = dst[e];
        int pos = rowptr[d] + atomicAdd(&fill[d], 1);
        col[pos] = src[e];
    }
}

// ---- gptr[g] = lower_bound(batch, g)  (batch sorted) ----
__global__ void k_gptr(const int* __restrict__ batch, int* __restrict__ gptr) {
    int g = blockIdx.x * 256 + threadIdx.x;
    if (g > NG) return;
    if (g == NG) { gptr[NG] = N_NODES; return; }
    int lo = 0, hi = N_NODES;
    while (lo < hi) {
        int mid = (lo + hi) >> 1;
        if (batch[mid] < g) lo = mid + 1; else hi = mid;
    }
    gptr[g] = lo;
}

// ---- transpose W [K x 256] f32 -> Wt [256 x KP] bf16, zero-padded ----
__global__ void k_transpose_w(const float* __restrict__ W, u16* __restrict__ Wt, int K, int KP) {
    int k = blockIdx.x;
    int n = threadIdx.x;
    Wt[(size_t)n * KP + k] = (k < K) ? f2b(W[(size_t)k * HID + n]) : (u16)0;
}

// ---- pad x [N x 69] f32 -> Xpad [N x 96] bf16 ----
__global__ void k_pad_x(const float* __restrict__ x, u16* __restrict__ xp) {
    int m = blockIdx.x;
    int j = threadIdx.x;
    if (j < KP1) xp[(size_t)m * KP1 + j] = (j < IN_DIM) ? f2b(x[(size_t)m * IN_DIM + j]) : (u16)0;
}

// ---- GEMM: g = dinv[m] * (A @ Wt^T), bf16 out ----
__global__ __launch_bounds__(256) void k_gemm(const u16* __restrict__ A, int KP, int M,
                                              const u16* __restrict__ Wt,
                                              const float* __restrict__ dinv,
                                              u16* __restrict__ Gout) {
    __shared__ __align__(16) u16 As[64 * 40];
    __shared__ __align__(16) u16 Bs[256 * 40];

    const int tid  = threadIdx.x;
    const int wave = tid >> 6;
    const int lane = tid & 63;
    const int quad = lane >> 4;
    const int lm   = lane & 15;
    const int m0   = blockIdx.x * 64;

    f32x4 acc[4][4] = {};

    const int ar = tid >> 2;
    const int ai = (tid & 3) * 8;

    for (int kt = 0; kt < KP; kt += 32) {
        __syncthreads();
        {
            int m = m0 + ar;
            uint4 v = make_uint4(0, 0, 0, 0);
            if (m < M) v = *(const uint4*)(A + (size_t)m * KP + kt + ai);
            *(uint4*)(As + ar * 40 + ai) = v;
        }
        #pragma unroll
        for (int p = 0; p < 4; ++p) {
            int n = p * 64 + (tid >> 2);
            uint4 v = *(const uint4*)(Wt + (size_t)n * KP + kt + ai);
            *(uint4*)(Bs + n * 40 + ai) = v;
        }
        __syncthreads();

        bf16x8 af[4], bfr[4];
        #pragma unroll
        for (int rt = 0; rt < 4; ++rt)
            af[rt] = *(const bf16x8*)(As + (rt * 16 + lm) * 40 + quad * 8);
        #pragma unroll
        for (int ct = 0; ct < 4; ++ct)
            bfr[ct] = *(const bf16x8*)(Bs + (wave * 64 + ct * 16 + lm) * 40 + quad * 8);
        #pragma unroll
        for (int rt = 0; rt < 4; ++rt)
            #pragma unroll
            for (int ct = 0; ct < 4; ++ct)
                acc[rt][ct] = __builtin_amdgcn_mfma_f32_16x16x32_bf16(af[rt], bfr[ct], acc[rt][ct], 0, 0, 0);
    }

    #pragma unroll
    for (int rt = 0; rt < 4; ++rt) {
        #pragma unroll
        for (int reg = 0; reg < 4; ++reg) {
            int m = m0 + rt * 16 + quad * 4 + reg;
            if (m >= M) continue;
            float dv = dinv[m];
            #pragma unroll
            for (int ct = 0; ct < 4; ++ct) {
                int n = wave * 64 + ct * 16 + lm;
                Gout[(size_t)m * HID + n] = f2b(dv * acc[rt][ct][reg]);
            }
        }
    }
}

// ---- aggregate: h[d] = dinv[d]*(g[d] + sum_{s->d} g[s]) + b ----
// one wave per node, lane owns 4 dims; edge loop unrolled x4 for MLP.
// MODE 0: relu -> Xout (bf16). MODE 1: h4 -> Hout (f32), no relu.
template<int MODE>
__global__ __launch_bounds__(256) void k_agg(const int* __restrict__ rowptr,
                                             const int* __restrict__ col,
                                             const u16* __restrict__ g,
                                             const float* __restrict__ dinv,
                                             const float* __restrict__ bias,
                                             u16* __restrict__ Xout,
                                             float* __restrict__ Hout) {
    int node = blockIdx.x * 4 + (threadIdx.x >> 6);
    if (node >= N_NODES) return;
    int lane = threadIdx.x & 63;
    int j = lane * 4;
    const u16* gj = g + j;

    float a0, a1, a2, a3;
    {   // self-loop term
        uint2 v = *(const uint2*)(gj + (size_t)node * HID);
        a0 = lo16(v.x); a1 = hi16(v.x); a2 = lo16(v.y); a3 = hi16(v.y);
    }
    int e = rowptr[node], end = rowptr[node + 1];
    for (; e + 4 <= end; e += 4) {
        int s0 = col[e], s1 = col[e + 1], s2 = col[e + 2], s3 = col[e + 3];
        uint2 w0 = *(const uint2*)(gj + (size_t)s0 * HID);
        uint2 w1 = *(const uint2*)(gj + (size_t)s1 * HID);
        uint2 w2 = *(const uint2*)(gj + (size_t)s2 * HID);
        uint2 w3 = *(const uint2*)(gj + (size_t)s3 * HID);
        a0 += (lo16(w0.x) + lo16(w1.x)) + (lo16(w2.x) + lo16(w3.x));
        a1 += (hi16(w0.x) + hi16(w1.x)) + (hi16(w2.x) + hi16(w3.x));
        a2 += (lo16(w0.y) + lo16(w1.y)) + (lo16(w2.y) + lo16(w3.y));
        a3 += (hi16(w0.y) + hi16(w1.y)) + (hi16(w2.y) + hi16(w3.y));
    }
    for (; e < end; ++e) {
        int s = col[e];
        uint2 w = *(const uint2*)(gj + (size_t)s * HID);
        a0 += lo16(w.x); a1 += hi16(w.x); a2 += lo16(w.y); a3 += hi16(w.y);
    }
    float dv = dinv[node];
    float4 bb = *(const float4*)(bias + j);
    a0 = fmaf(a0, dv, bb.x); a1 = fmaf(a1, dv, bb.y);
    a2 = fmaf(a2, dv, bb.z); a3 = fmaf(a3, dv, bb.w);

    if (MODE == 0) {
        a0 = fmaxf(a0, 0.0f); a1 = fmaxf(a1, 0.0f);
        a2 = fmaxf(a2, 0.0f); a3 = fmaxf(a3, 0.0f);
        uint2 o;
        o.x = (u32)f2b(a0) | ((u32)f2b(a1) << 16);
        o.y = (u32)f2b(a2) | ((u32)f2b(a3) << 16);
        *(uint2*)(Xout + (size_t)node * HID + j) = o;
    } else {
        *(float4*)(Hout + (size_t)node * HID + j) = make_float4(a0, a1, a2, a3);
    }
}

// ---- fused mean-pool + head: out[g][c] = (mean over nodes of h4) @ Wl + bl ----
__global__ __launch_bounds__(256) void k_pool_final(const float* __restrict__ H,
                                                    const int* __restrict__ gptr,
                                                    const float* __restrict__ Wl,
                                                    const float* __restrict__ bl,
                                                    float* __restrict__ out) {
    __shared__ float s0[256], s1[256];
    int gph = blockIdx.x;
    int j = threadIdx.x;
    int b = gptr[gph], e = gptr[gph + 1];
    float acc = 0.0f;
    for (int n = b; n < e; ++n) acc += H[(size_t)n * HID + j];
    float p = acc / fmaxf((float)(e - b), 1.0f);
    s0[j] = p * Wl[j * 2 + 0];
    s1[j] = p * Wl[j * 2 + 1];
    __syncthreads();
    for (int off = 128; off >= 1; off >>= 1) {
        if (j < off) { s0[j] += s0[j + off]; s1[j] += s1[j + off]; }
        __syncthreads();
    }
    if (j == 0) {
        out[gph * 2 + 0] = s0[0] + bl[0];
        out[gph * 2 + 1] = s1[0] + bl[1];
    }
}

extern "C" void kernel_launch(void* const* d_in, const int* in_sizes, int n_in,
                              void* d_out, int out_size, void* d_ws, size_t ws_size,
                              hipStream_t stream) {
    const float* x   = (const float*)d_in[0];
    const int* ei    = (const int*)d_in[1];
    const int* src   = ei;
    const int* dst   = ei + N_EDGES;
    const int* batch = (const int*)d_in[2];
    const float* W1 = (const float*)d_in[3];  const float* b1 = (const float*)d_in[4];
    const float* W2 = (const float*)d_in[5];  const float* b2 = (const float*)d_in[6];
    const float* W3 = (const float*)d_in[7];  const float* b3 = (const float*)d_in[8];
    const float* W4 = (const float*)d_in[9];  const float* b4 = (const float*)d_in[10];
    const float* Wl = (const float*)d_in[11]; const float* bl = (const float*)d_in[12];
    float* out = (float*)d_out;

    // ---- workspace layout ----
    char* p = (char*)d_ws;
    auto take = [&](size_t bytes) { char* r = p; p += (bytes + 255) & ~(size_t)255; return r; };
    // contiguous zero block: deg(int) | fill(int)
    size_t zbytes = (size_t)(N_NODES + N_NODES) * 4;
    int*   deg  = (int*)take(zbytes);
    int*   fill = deg + N_NODES;
    float* dinv = (float*)take((size_t)N_NODES * sizeof(float));
    int* rowptr = (int*)take((size_t)(N_NODES + 1) * sizeof(int));
    int* col    = (int*)take((size_t)N_EDGES * sizeof(int));
    int* bsum   = (int*)take((size_t)SCAN_B * sizeof(int));
    int* boff   = (int*)take((size_t)SCAN_B * sizeof(int));
    int* gptr   = (int*)take((size_t)(NG + 1) * sizeof(int));
    u16* Wt1 = (u16*)take((size_t)HID * KP1 * 2);
    u16* Wt2 = (u16*)take((size_t)HID * HID * 2);
    u16* Wt3 = (u16*)take((size_t)HID * HID * 2);
    u16* Wt4 = (u16*)take((size_t)HID * HID * 2);
    u16* Gbuf = (u16*)take((size_t)N_NODES * HID * 2);
    u16* Xbuf = (u16*)take((size_t)N_NODES * HID * 2);
    float* Hbuf = (float*)take((size_t)N_NODES * HID * sizeof(float));
    u16* Xpad = Xbuf;   // alias: layer-1 padded input dead before Xbuf first written

    hipMemsetAsync(deg, 0, zbytes, stream);

    // CSR build + norms + graph ranges
    k_deg<<<(N_EDGES + 255) / 256, 256, 0, stream>>>(dst, deg);
    k_scan_local<<<SCAN_B, 256, 0, stream>>>(deg, rowptr, bsum);
    k_scan_bsum<<<1, 512, 0, stream>>>(bsum, boff);
    k_scan_add<<<SCAN_B, 256, 0, stream>>>(rowptr, boff);
    k_fill<<<(N_EDGES + 255) / 256, 256, 0, stream>>>(src, dst, rowptr, fill, col);
    k_dinv<<<(N_NODES + 255) / 256, 256, 0, stream>>>(deg, dinv);
    k_gptr<<<(NG + 256) / 256, 256, 0, stream>>>(batch, gptr);

    k_transpose_w<<<KP1, 256, 0, stream>>>(W1, Wt1, IN_DIM, KP1);
    k_transpose_w<<<HID, 256, 0, stream>>>(W2, Wt2, HID, HID);
    k_transpose_w<<<HID, 256, 0, stream>>>(W3, Wt3, HID, HID);
    k_transpose_w<<<HID, 256, 0, stream>>>(W4, Wt4, HID, HID);
    k_pad_x<<<N_NODES, 128, 0, stream>>>(x, Xpad);

    const int gemm_grid = (N_NODES + 63) / 64;
    const int agg_grid  = (N_NODES + 3) / 4;

    // layer 1
    k_gemm<<<gemm_grid, 256, 0, stream>>>(Xpad, KP1, N_NODES, Wt1, dinv, Gbuf);
    k_agg<0><<<agg_grid, 256, 0, stream>>>(rowptr, col, Gbuf, dinv, b1, Xbuf, Hbuf);
    // layer 2
    k_gemm<<<gemm_grid, 256, 0, stream>>>(Xbuf, HID, N_NODES, Wt2, dinv, Gbuf);
    k_agg<0><<<agg_grid, 256, 0, stream>>>(rowptr, col, Gbuf, dinv, b2, Xbuf, Hbuf);
    // layer 3
    k_gemm<<<gemm_grid, 256, 0, stream>>>(Xbuf, HID, N_NODES, Wt3, dinv, Gbuf);
    k_agg<0><<<agg_grid, 256, 0, stream>>>(rowptr, col, Gbuf, dinv, b3, Xbuf, Hbuf);
    // layer 4: h4 -> Hbuf (f32), then fused mean-pool + head
    k_gemm<<<gemm_grid, 256, 0, stream>>>(Xbuf, HID, N_NODES, Wt4, dinv, Gbuf);
    k_agg<1><<<agg_grid, 256, 0, stream>>>(rowptr, col, Gbuf, dinv, b4, Xbuf, Hbuf);
    k_pool_final<<<NG, 256, 0, stream>>>(Hbuf, gptr, Wl, bl, out);
}

// Round 5
// 440.132 us; speedup vs baseline: 4.1940x; 1.2185x over previous
//
#include <hip/hip_runtime.h>
#include <hip/hip_bf16.h>

#define N_NODES 100000
#define N_EDGES 400000
#define IN_DIM  69
#define KP1     96      // IN_DIM padded to multiple of 32
#define HID     256
#define NG      4096
#define SCAN_B  391     // ceil(N_NODES / 256)

typedef __attribute__((ext_vector_type(8))) short bf16x8;
typedef __attribute__((ext_vector_type(4))) float f32x4;
typedef unsigned short u16;
typedef unsigned int   u32;

__device__ __forceinline__ float b2f(u16 v) {
    u32 x = ((u32)v) << 16;
    return __builtin_bit_cast(float, x);
}
__device__ __forceinline__ u16 f2b(float f) {
    u32 x = __builtin_bit_cast(u32, f);
    u32 r = (x + 0x7FFF + ((x >> 16) & 1)) >> 16;   // RNE
    return (u16)r;
}
__device__ __forceinline__ float lo16(u32 v) { return b2f((u16)(v & 0xffff)); }
__device__ __forceinline__ float hi16(u32 v) { return b2f((u16)(v >> 16)); }

// ---- in-degree count (int) ----
__global__ void k_deg(const int* __restrict__ dst, int* __restrict__ deg) {
    int e = blockIdx.x * blockDim.x + threadIdx.x;
    if (e < N_EDGES) atomicAdd(&deg[dst[e]], 1);
}

// ---- dinv = rsqrt(deg+1) ----
__global__ void k_dinv(const int* __restrict__ deg, float* __restrict__ dinv) {
    int n = blockIdx.x * blockDim.x + threadIdx.x;
    if (n < N_NODES) dinv[n] = rsqrtf((float)deg[n] + 1.0f);
}

// ---- two-level exclusive scan of deg -> rowptr ----
__global__ void k_scan_local(const int* __restrict__ deg, int* __restrict__ rowptr,
                             int* __restrict__ bsum) {
    __shared__ int s[256];
    int tid = threadIdx.x;
    int i = blockIdx.x * 256 + tid;
    int v = (i < N_NODES) ? deg[i] : 0;
    s[tid] = v;
    __syncthreads();
    #pragma unroll
    for (int off = 1; off < 256; off <<= 1) {
        int t = 0;
        if (tid >= off) t = s[tid - off];
        __syncthreads();
        if (tid >= off) s[tid] += t;
        __syncthreads();
    }
    if (i < N_NODES) rowptr[i] = s[tid] - v;          // exclusive
    if (tid == 255) bsum[blockIdx.x] = s[255];        // block total
}

__global__ void k_scan_bsum(int* __restrict__ bsum, int* __restrict__ boff) {
    __shared__ int s[512];
    int tid = threadIdx.x;
    int v = (tid < SCAN_B) ? bsum[tid] : 0;
    s[tid] = v;
    __syncthreads();
    #pragma unroll
    for (int off = 1; off < 512; off <<= 1) {
        int t = 0;
        if (tid >= off) t = s[tid - off];
        __syncthreads();
        if (tid >= off) s[tid] += t;
        __syncthreads();
    }
    if (tid < SCAN_B) boff[tid] = s[tid] - v;         // exclusive
}

__global__ void k_scan_add(int* __restrict__ rowptr, const int* __restrict__ boff) {
    int i = blockIdx.x * 256 + threadIdx.x;
    if (i < N_NODES) rowptr[i] += boff[blockIdx.x];
    if (i == 0) rowptr[N_NODES] = N_EDGES;
}

// ---- CSR fill ----
__global__ void k_fill(const int* __restrict__ src, const int* __restrict__ dst,
                       const int* __restrict__ rowptr, int* __restrict__ fill,
                       int* __restrict__ col) {
    int e = blockIdx.x * blockDim.x + threadIdx.x;
    if (e < N_EDGES) {
        int d = dst[e];
        int pos = rowptr[d] + atomicAdd(&fill[d], 1);
        col[pos] = src[e];
    }
}

// ---- gptr[g] = lower_bound(batch, g)  (batch sorted) ----
__global__ void k_gptr(const int* __restrict__ batch, int* __restrict__ gptr) {
    int g = blockIdx.x * 256 + threadIdx.x;
    if (g > NG) return;
    if (g == NG) { gptr[NG] = N_NODES; return; }
    int lo = 0, hi = N_NODES;
    while (lo < hi) {
        int mid = (lo + hi) >> 1;
        if (batch[mid] < g) lo = mid + 1; else hi = mid;
    }
    gptr[g] = lo;
}

// ---- transpose W [K x 256] f32 -> Wt [256 x KP] bf16, zero-padded ----
__global__ void k_transpose_w(const float* __restrict__ W, u16* __restrict__ Wt, int K, int KP) {
    int k = blockIdx.x;
    int n = threadIdx.x;
    Wt[(size_t)n * KP + k] = (k < K) ? f2b(W[(size_t)k * HID + n]) : (u16)0;
}

// ---- Xs = dinv .* x, padded [N x 96] bf16. wave/node, lanes 0..47 own 2 dims ----
__global__ __launch_bounds__(256) void k_pad_scale(const float* __restrict__ x,
                                                   const float* __restrict__ dinv,
                                                   u16* __restrict__ xs) {
    int node = blockIdx.x * 4 + (threadIdx.x >> 6);
    if (node >= N_NODES) return;
    int lane = threadIdx.x & 63;
    if (lane >= 48) return;
    int d0 = lane * 2, d1 = lane * 2 + 1;
    float dv = dinv[node];
    const float* xr = x + (size_t)node * IN_DIM;
    float v0 = (d0 < IN_DIM) ? xr[d0] * dv : 0.0f;
    float v1 = (d1 < IN_DIM) ? xr[d1] * dv : 0.0f;
    u32 o = (u32)f2b(v0) | ((u32)f2b(v1) << 16);
    *(u32*)(xs + (size_t)node * KP1 + d0) = o;
}

// ---- 96-dim aggregate: Xa[d] = dinv[d]*(Xs[d] + sum_{s->d} Xs[s]) ----
__global__ __launch_bounds__(256) void k_agg96(const int* __restrict__ rowptr,
                                               const int* __restrict__ col,
                                               const u16* __restrict__ xs,
                                               const float* __restrict__ dinv,
                                               u16* __restrict__ xa) {
    int node = blockIdx.x * 4 + (threadIdx.x >> 6);
    if (node >= N_NODES) return;
    int lane = threadIdx.x & 63;
    if (lane >= 48) return;
    int j = lane * 2;

    u32 v = *(const u32*)(xs + (size_t)node * KP1 + j);
    float a0 = lo16(v), a1 = hi16(v);
    int e = rowptr[node], end = rowptr[node + 1];
    for (; e + 4 <= end; e += 4) {
        int s0 = col[e], s1 = col[e + 1], s2 = col[e + 2], s3 = col[e + 3];
        u32 w0 = *(const u32*)(xs + (size_t)s0 * KP1 + j);
        u32 w1 = *(const u32*)(xs + (size_t)s1 * KP1 + j);
        u32 w2 = *(const u32*)(xs + (size_t)s2 * KP1 + j);
        u32 w3 = *(const u32*)(xs + (size_t)s3 * KP1 + j);
        a0 += (lo16(w0) + lo16(w1)) + (lo16(w2) + lo16(w3));
        a1 += (hi16(w0) + hi16(w1)) + (hi16(w2) + hi16(w3));
    }
    for (; e < end; ++e) {
        u32 w = *(const u32*)(xs + (size_t)col[e] * KP1 + j);
        a0 += lo16(w); a1 += hi16(w);
    }
    float dv = dinv[node];
    u32 o = (u32)f2b(a0 * dv) | ((u32)f2b(a1 * dv) << 16);
    *(u32*)(xa + (size_t)node * KP1 + j) = o;
}

// ---- GEMM: MODE 0: out = dinv[m]*(A@Wt^T)      (g for layers 2,3)
//            MODE 1: out = relu(A@Wt^T + bias)   (layer-1 fused epilogue) ----
template<int MODE>
__global__ __launch_bounds__(256) void k_gemm(const u16* __restrict__ A, int KP, int M,
                                              const u16* __restrict__ Wt,
                                              const float* __restrict__ dinv,
                                              const float* __restrict__ bias,
                                              u16* __restrict__ Out) {
    __shared__ __align__(16) u16 As[64 * 40];
    __shared__ __align__(16) u16 Bs[256 * 40];

    const int tid  = threadIdx.x;
    const int wave = tid >> 6;
    const int lane = tid & 63;
    const int quad = lane >> 4;
    const int lm   = lane & 15;
    const int m0   = blockIdx.x * 64;

    f32x4 acc[4][4] = {};

    const int ar = tid >> 2;
    const int ai = (tid & 3) * 8;

    for (int kt = 0; kt < KP; kt += 32) {
        __syncthreads();
        {
            int m = m0 + ar;
            uint4 v = make_uint4(0, 0, 0, 0);
            if (m < M) v = *(const uint4*)(A + (size_t)m * KP + kt + ai);
            *(uint4*)(As + ar * 40 + ai) = v;
        }
        #pragma unroll
        for (int p = 0; p < 4; ++p) {
            int n = p * 64 + (tid >> 2);
            uint4 v = *(const uint4*)(Wt + (size_t)n * KP + kt + ai);
            *(uint4*)(Bs + n * 40 + ai) = v;
        }
        __syncthreads();

        bf16x8 af[4], bfr[4];
        #pragma unroll
        for (int rt = 0; rt < 4; ++rt)
            af[rt] = *(const bf16x8*)(As + (rt * 16 + lm) * 40 + quad * 8);
        #pragma unroll
        for (int ct = 0; ct < 4; ++ct)
            bfr[ct] = *(const bf16x8*)(Bs + (wave * 64 + ct * 16 + lm) * 40 + quad * 8);
        #pragma unroll
        for (int rt = 0; rt < 4; ++rt)
            #pragma unroll
            for (int ct = 0; ct < 4; ++ct)
                acc[rt][ct] = __builtin_amdgcn_mfma_f32_16x16x32_bf16(af[rt], bfr[ct], acc[rt][ct], 0, 0, 0);
    }

    #pragma unroll
    for (int rt = 0; rt < 4; ++rt) {
        #pragma unroll
        for (int reg = 0; reg < 4; ++reg) {
            int m = m0 + rt * 16 + quad * 4 + reg;
            if (m >= M) continue;
            float dv = (MODE == 0) ? dinv[m] : 0.0f;
            #pragma unroll
            for (int ct = 0; ct < 4; ++ct) {
                int n = wave * 64 + ct * 16 + lm;
                float v = acc[rt][ct][reg];
                if (MODE == 0) v *= dv;
                else           v = fmaxf(v + bias[n], 0.0f);
                Out[(size_t)m * HID + n] = f2b(v);
            }
        }
    }
}

// ---- 256-dim aggregate + bias + relu -> bf16 X' (layers 2,3) ----
__global__ __launch_bounds__(256) void k_agg256(const int* __restrict__ rowptr,
                                                const int* __restrict__ col,
                                                const u16* __restrict__ g,
                                                const float* __restrict__ dinv,
                                                const float* __restrict__ bias,
                                                u16* __restrict__ Xout) {
    int node = blockIdx.x * 4 + (threadIdx.x >> 6);
    if (node >= N_NODES) return;
    int lane = threadIdx.x & 63;
    int j = lane * 4;
    const u16* gj = g + j;

    float a0, a1, a2, a3;
    {
        uint2 v = *(const uint2*)(gj + (size_t)node * HID);
        a0 = lo16(v.x); a1 = hi16(v.x); a2 = lo16(v.y); a3 = hi16(v.y);
    }
    int e = rowptr[node], end = rowptr[node + 1];
    for (; e + 4 <= end; e += 4) {
        int s0 = col[e], s1 = col[e + 1], s2 = col[e + 2], s3 = col[e + 3];
        uint2 w0 = *(const uint2*)(gj + (size_t)s0 * HID);
        uint2 w1 = *(const uint2*)(gj + (size_t)s1 * HID);
        uint2 w2 = *(const uint2*)(gj + (size_t)s2 * HID);
        uint2 w3 = *(const uint2*)(gj + (size_t)s3 * HID);
        a0 += (lo16(w0.x) + lo16(w1.x)) + (lo16(w2.x) + lo16(w3.x));
        a1 += (hi16(w0.x) + hi16(w1.x)) + (hi16(w2.x) + hi16(w3.x));
        a2 += (lo16(w0.y) + lo16(w1.y)) + (lo16(w2.y) + lo16(w3.y));
        a3 += (hi16(w0.y) + hi16(w1.y)) + (hi16(w2.y) + hi16(w3.y));
    }
    for (; e < end; ++e) {
        int s = col[e];
        uint2 w = *(const uint2*)(gj + (size_t)s * HID);
        a0 += lo16(w.x); a1 += hi16(w.x); a2 += lo16(w.y); a3 += hi16(w.y);
    }
    float dv = dinv[node];
    float4 bb = *(const float4*)(bias + j);
    a0 = fmaxf(fmaf(a0, dv, bb.x), 0.0f);
    a1 = fmaxf(fmaf(a1, dv, bb.y), 0.0f);
    a2 = fmaxf(fmaf(a2, dv, bb.z), 0.0f);
    a3 = fmaxf(fmaf(a3, dv, bb.w), 0.0f);
    uint2 o;
    o.x = (u32)f2b(a0) | ((u32)f2b(a1) << 16);
    o.y = (u32)f2b(a2) | ((u32)f2b(a3) << 16);
    *(uint2*)(Xout + (size_t)node * HID + j) = o;
}

// ---- W4l = W4 @ Wl (f32 256x2); c4 = b4 @ Wl + bl ----
__global__ void k_w4l(const float* __restrict__ W4, const float* __restrict__ Wl,
                      const float* __restrict__ b4, const float* __restrict__ bl,
                      float* __restrict__ W4l, float* __restrict__ c4) {
    int k = threadIdx.x;            // 0..255
    float s0 = 0.0f, s1 = 0.0f;
    const float* wr = W4 + (size_t)k * HID;
    for (int j = 0; j < HID; ++j) {
        float w = wr[j];
        s0 += w * Wl[j * 2 + 0];
        s1 += w * Wl[j * 2 + 1];
    }
    W4l[k * 2 + 0] = s0;
    W4l[k * 2 + 1] = s1;
    if (k < 2) {
        float s = bl[k];
        for (int j = 0; j < HID; ++j) s += b4[j] * Wl[j * 2 + k];
        c4[k] = s;
    }
}

// ---- g4 = dinv .* (X4 @ W4l)  [N x 2] f32. wave/node, shfl reduce ----
__global__ __launch_bounds__(256) void k_gemm2col(const u16* __restrict__ X,
                                                  const float* __restrict__ W4l,
                                                  const float* __restrict__ dinv,
                                                  float* __restrict__ g4) {
    __shared__ float2 sW[HID];
    int tid = threadIdx.x;
    sW[tid] = *(const float2*)(W4l + tid * 2);
    __syncthreads();

    int node = blockIdx.x * 4 + (tid >> 6);
    if (node >= N_NODES) return;
    int lane = tid & 63;
    uint2 v = *(const uint2*)(X + (size_t)node * HID + lane * 4);
    float x0 = lo16(v.x), x1 = hi16(v.x), x2 = lo16(v.y), x3 = hi16(v.y);
    float2 w0 = sW[lane * 4 + 0], w1 = sW[lane * 4 + 1];
    float2 w2 = sW[lane * 4 + 2], w3 = sW[lane * 4 + 3];
    float s0 = x0 * w0.x + x1 * w1.x + x2 * w2.x + x3 * w3.x;
    float s1 = x0 * w0.y + x1 * w1.y + x2 * w2.y + x3 * w3.y;
    #pragma unroll
    for (int off = 32; off >= 1; off >>= 1) {
        s0 += __shfl_down(s0, off);
        s1 += __shfl_down(s1, off);
    }
    if (lane == 0) {
        float dv = dinv[node];
        *(float2*)(g4 + (size_t)node * 2) = make_float2(s0 * dv, s1 * dv);
    }
}

// ---- 2-dim aggregate: h4[d] = dinv[d]*(g4[d] + sum g4[s]) ----
__global__ void k_agg2(const int* __restrict__ rowptr, const int* __restrict__ col,
                       const float* __restrict__ g4, const float* __restrict__ dinv,
                       float* __restrict__ h4) {
    int node = blockIdx.x * blockDim.x + threadIdx.x;
    if (node >= N_NODES) return;
    float2 a = *(const float2*)(g4 + (size_t)node * 2);
    int e = rowptr[node], end = rowptr[node + 1];
    for (; e < end; ++e) {
        float2 w = *(const float2*)(g4 + (size_t)col[e] * 2);
        a.x += w.x; a.y += w.y;
    }
    float dv = dinv[node];
    *(float2*)(h4 + (size_t)node * 2) = make_float2(a.x * dv, a.y * dv);
}

// ---- per-graph mean of h4 + c4 -> out [NG x 2] f32. wave/graph ----
__global__ __launch_bounds__(256) void k_pool2(const float* __restrict__ h4,
                                               const int* __restrict__ gptr,
                                               const float* __restrict__ c4,
                                               float* __restrict__ out) {
    int gph = blockIdx.x * 4 + (threadIdx.x >> 6);
    if (gph >= NG) return;
    int lane = threadIdx.x & 63;
    int b = gptr[gph], e = gptr[gph + 1];
    float s0 = 0.0f, s1 = 0.0f;
    for (int n = b + lane; n < e; n += 64) {
        float2 v = *(const float2*)(h4 + (size_t)n * 2);
        s0 += v.x; s1 += v.y;
    }
    #pragma unroll
    for (int off = 32; off >= 1; off >>= 1) {
        s0 += __shfl_down(s0, off);
        s1 += __shfl_down(s1, off);
    }
    if (lane == 0) {
        float inv = 1.0f / fmaxf((float)(e - b), 1.0f);
        out[gph * 2 + 0] = s0 * inv + c4[0];
        out[gph * 2 + 1] = s1 * inv + c4[1];
    }
}

extern "C" void kernel_launch(void* const* d_in, const int* in_sizes, int n_in,
                              void* d_out, int out_size, void* d_ws, size_t ws_size,
                              hipStream_t stream) {
    const float* x   = (const float*)d_in[0];
    const int* ei    = (const int*)d_in[1];
    const int* src   = ei;
    const int* dst   = ei + N_EDGES;
    const int* batch = (const int*)d_in[2];
    const float* W1 = (const float*)d_in[3];  const float* b1 = (const float*)d_in[4];
    const float* W2 = (const float*)d_in[5];  const float* b2 = (const float*)d_in[6];
    const float* W3 = (const float*)d_in[7];  const float* b3 = (const float*)d_in[8];
    const float* W4 = (const float*)d_in[9];  const float* b4 = (const float*)d_in[10];
    const float* Wl = (const float*)d_in[11]; const float* bl = (const float*)d_in[12];
    float* out = (float*)d_out;

    // ---- workspace layout ----
    char* p = (char*)d_ws;
    auto take = [&](size_t bytes) { char* r = p; p += (bytes + 255) & ~(size_t)255; return r; };
    size_t zbytes = (size_t)(N_NODES + N_NODES) * 4;   // deg | fill
    int*   deg  = (int*)take(zbytes);
    int*   fill = deg + N_NODES;
    float* dinv = (float*)take((size_t)N_NODES * sizeof(float));
    int* rowptr = (int*)take((size_t)(N_NODES + 1) * sizeof(int));
    int* col    = (int*)take((size_t)N_EDGES * sizeof(int));
    int* bsum   = (int*)take((size_t)SCAN_B * sizeof(int));
    int* boff   = (int*)take((size_t)SCAN_B * sizeof(int));
    int* gptr   = (int*)take((size_t)(NG + 1) * sizeof(int));
    float* W4l  = (float*)take((size_t)HID * 2 * sizeof(float));
    float* c4   = (float*)take(2 * sizeof(float));
    float* g4   = (float*)take((size_t)N_NODES * 2 * sizeof(float));
    float* h4   = (float*)take((size_t)N_NODES * 2 * sizeof(float));
    u16* Wt1 = (u16*)take((size_t)HID * KP1 * 2);
    u16* Wt2 = (u16*)take((size_t)HID * HID * 2);
    u16* Wt3 = (u16*)take((size_t)HID * HID * 2);
    u16* Xs  = (u16*)take((size_t)N_NODES * KP1 * 2);
    u16* Xa  = (u16*)take((size_t)N_NODES * KP1 * 2);
    u16* Gbuf = (u16*)take((size_t)N_NODES * HID * 2);
    u16* Xbuf = (u16*)take((size_t)N_NODES * HID * 2);

    hipMemsetAsync(deg, 0, zbytes, stream);

    // CSR build + norms + graph ranges
    k_deg<<<(N_EDGES + 255) / 256, 256, 0, stream>>>(dst, deg);
    k_scan_local<<<SCAN_B, 256, 0, stream>>>(deg, rowptr, bsum);
    k_scan_bsum<<<1, 512, 0, stream>>>(bsum, boff);
    k_scan_add<<<SCAN_B, 256, 0, stream>>>(rowptr, boff);
    k_fill<<<(N_EDGES + 255) / 256, 256, 0, stream>>>(src, dst, rowptr, fill, col);
    k_dinv<<<(N_NODES + 255) / 256, 256, 0, stream>>>(deg, dinv);
    k_gptr<<<(NG + 256) / 256, 256, 0, stream>>>(batch, gptr);

    k_transpose_w<<<KP1, 256, 0, stream>>>(W1, Wt1, IN_DIM, KP1);
    k_transpose_w<<<HID, 256, 0, stream>>>(W2, Wt2, HID, HID);
    k_transpose_w<<<HID, 256, 0, stream>>>(W3, Wt3, HID, HID);
    k_w4l<<<1, 256, 0, stream>>>(W4, Wl, b4, bl, W4l, c4);

    const int gemm_grid = (N_NODES + 63) / 64;
    const int nb4       = (N_NODES + 3) / 4;

    // layer 1: aggregate-first in 96-dim input space, relu+bias fused in GEMM
    k_pad_scale<<<nb4, 256, 0, stream>>>(x, dinv, Xs);
    k_agg96<<<nb4, 256, 0, stream>>>(rowptr, col, Xs, dinv, Xa);
    k_gemm<1><<<gemm_grid, 256, 0, stream>>>(Xa, KP1, N_NODES, Wt1, dinv, b1, Xbuf);
    // layer 2
    k_gemm<0><<<gemm_grid, 256, 0, stream>>>(Xbuf, HID, N_NODES, Wt2, dinv, b2, Gbuf);
    k_agg256<<<nb4, 256, 0, stream>>>(rowptr, col, Gbuf, dinv, b2, Xbuf);
    // layer 3
    k_gemm<0><<<gemm_grid, 256, 0, stream>>>(Xbuf, HID, N_NODES, Wt3, dinv, b3, Gbuf);
    k_agg256<<<nb4, 256, 0, stream>>>(rowptr, col, Gbuf, dinv, b3, Xbuf);
    // layer 4 + head, collapsed to 2 dims
    k_gemm2col<<<nb4, 256, 0, stream>>>(Xbuf, W4l, dinv, g4);
    k_agg2<<<(N_NODES + 255) / 256, 256, 0, stream>>>(rowptr, col, g4, dinv, h4);
    k_pool2<<<(NG + 3) / 4, 256, 0, stream>>>(h4, gptr, c4, out);
}

// Round 6
// 426.986 us; speedup vs baseline: 4.3231x; 1.0308x over previous
//
#include <hip/hip_runtime.h>
#include <hip/hip_bf16.h>

#define N_NODES 100000
#define M_PAD   100096   // 782 * 128, so 128-row GEMM tiles never read OOB
#define N_EDGES 400000
#define IN_DIM  69
#define KPX     96       // Xs pitch (gather space for layer-1 aggregate)
#define KPA     128      // Xa pitch (layer-1 GEMM K, padded to BK multiple)
#define HID     256
#define NG      4096
#define SCAN_B  391      // ceil(N_NODES / 256)

typedef __attribute__((ext_vector_type(8))) short bf16x8;
typedef __attribute__((ext_vector_type(4))) float f32x4;
typedef unsigned short u16;
typedef unsigned int   u32;

__device__ __forceinline__ float b2f(u16 v) {
    u32 x = ((u32)v) << 16;
    return __builtin_bit_cast(float, x);
}
__device__ __forceinline__ u16 f2b(float f) {
    u32 x = __builtin_bit_cast(u32, f);
    u32 r = (x + 0x7FFF + ((x >> 16) & 1)) >> 16;   // RNE
    return (u16)r;
}
__device__ __forceinline__ float lo16(u32 v) { return b2f((u16)(v & 0xffff)); }
__device__ __forceinline__ float hi16(u32 v) { return b2f((u16)(v >> 16)); }

// async global->LDS, 16B per lane; LDS dest = wave-uniform base + lane*16
__device__ __forceinline__ void gl_lds16(const u16* g, u16* l) {
    __builtin_amdgcn_global_load_lds(
        (const __attribute__((address_space(1))) void*)g,
        (__attribute__((address_space(3))) void*)l, 16, 0, 0);
}

// ---- in-degree count (int) ----
__global__ void k_deg(const int* __restrict__ dst, int* __restrict__ deg) {
    int e = blockIdx.x * blockDim.x + threadIdx.x;
    if (e < N_EDGES) atomicAdd(&deg[dst[e]], 1);
}

// ---- local scan + dinv fused ----
__global__ void k_scan_local(const int* __restrict__ deg, int* __restrict__ rowptr,
                             int* __restrict__ bsum, float* __restrict__ dinv) {
    __shared__ int s[256];
    int tid = threadIdx.x;
    int i = blockIdx.x * 256 + tid;
    int v = (i < N_NODES) ? deg[i] : 0;
    if (i < N_NODES) dinv[i] = rsqrtf((float)v + 1.0f);
    s[tid] = v;
    __syncthreads();
    #pragma unroll
    for (int off = 1; off < 256; off <<= 1) {
        int t = 0;
        if (tid >= off) t = s[tid - off];
        __syncthreads();
        if (tid >= off) s[tid] += t;
        __syncthreads();
    }
    if (i < N_NODES) rowptr[i] = s[tid] - v;          // exclusive
    if (tid == 255) bsum[blockIdx.x] = s[255];        // block total
}

__global__ void k_scan_bsum(int* __restrict__ bsum, int* __restrict__ boff) {
    __shared__ int s[512];
    int tid = threadIdx.x;
    int v = (tid < SCAN_B) ? bsum[tid] : 0;
    s[tid] = v;
    __syncthreads();
    #pragma unroll
    for (int off = 1; off < 512; off <<= 1) {
        int t = 0;
        if (tid >= off) t = s[tid - off];
        __syncthreads();
        if (tid >= off) s[tid] += t;
        __syncthreads();
    }
    if (tid < SCAN_B) boff[tid] = s[tid] - v;         // exclusive
}

__global__ void k_scan_add(int* __restrict__ rowptr, const int* __restrict__ boff) {
    int i = blockIdx.x * 256 + threadIdx.x;
    if (i < N_NODES) rowptr[i] += boff[blockIdx.x];
    if (i == 0) rowptr[N_NODES] = N_EDGES;
}

// ---- CSR fill ----
__global__ void k_fill(const int* __restrict__ src, const int* __restrict__ dst,
                       const int* __restrict__ rowptr, int* __restrict__ fill,
                       int* __restrict__ col) {
    int e = blockIdx.x * blockDim.x + threadIdx.x;
    if (e < N_EDGES) {
        int d = dst[e];
        int pos = rowptr[d] + atomicAdd(&fill[d], 1);
        col[pos] = src[e];
    }
}

// ---- merged prep: W1/W2/W3 transpose->bf16, W4@Wl fold, gptr search ----
__global__ void k_prep(const float* __restrict__ W1, const float* __restrict__ W2,
                       const float* __restrict__ W3, const float* __restrict__ W4,
                       const float* __restrict__ Wl, const float* __restrict__ b4,
                       const float* __restrict__ bl, const int* __restrict__ batch,
                       u16* __restrict__ Wt1, u16* __restrict__ Wt2, u16* __restrict__ Wt3,
                       float* __restrict__ W4l, float* __restrict__ c4, int* __restrict__ gptr) {
    int b = blockIdx.x;
    int t = threadIdx.x;
    if (b < KPA) {                       // Wt1 [256 x 128], zero-padded K
        Wt1[(size_t)t * KPA + b] = (b < IN_DIM) ? f2b(W1[(size_t)b * HID + t]) : (u16)0;
    } else if (b < KPA + HID) {          // Wt2 [256 x 256]
        int k = b - KPA;
        Wt2[(size_t)t * HID + k] = f2b(W2[(size_t)k * HID + t]);
    } else if (b < KPA + 2 * HID) {      // Wt3
        int k = b - KPA - HID;
        Wt3[(size_t)t * HID + k] = f2b(W3[(size_t)k * HID + t]);
    } else if (b == KPA + 2 * HID) {     // W4l = W4 @ Wl ; c4 = b4 @ Wl + bl
        float s0 = 0.0f, s1 = 0.0f;
        const float* wr = W4 + (size_t)t * HID;
        for (int j = 0; j < HID; ++j) {
            float w = wr[j];
            s0 += w * Wl[j * 2 + 0];
            s1 += w * Wl[j * 2 + 1];
        }
        W4l[t * 2 + 0] = s0;
        W4l[t * 2 + 1] = s1;
        if (t < 2) {
            float s = bl[t];
            for (int j = 0; j < HID; ++j) s += b4[j] * Wl[j * 2 + t];
            c4[t] = s;
        }
    } else {                             // gptr: lower_bound(batch, g)
        int g = (b - (KPA + 2 * HID + 1)) * 256 + t;
        if (g > NG) return;
        if (g == NG) { gptr[NG] = N_NODES; return; }
        int lo = 0, hi = N_NODES;
        while (lo < hi) {
            int mid = (lo + hi) >> 1;
            if (batch[mid] < g) lo = mid + 1; else hi = mid;
        }
        gptr[g] = lo;
    }
}

// ---- Xs = dinv .* x, [N x 96] bf16. wave/node, lanes 0..47 own 2 dims ----
__global__ __launch_bounds__(256) void k_pad_scale(const float* __restrict__ x,
                                                   const float* __restrict__ dinv,
                                                   u16* __restrict__ xs) {
    int node = blockIdx.x * 4 + (threadIdx.x >> 6);
    if (node >= N_NODES) return;
    int lane = threadIdx.x & 63;
    if (lane >= 48) return;
    int d0 = lane * 2, d1 = lane * 2 + 1;
    float dv = dinv[node];
    const float* xr = x + (size_t)node * IN_DIM;
    float v0 = (d0 < IN_DIM) ? xr[d0] * dv : 0.0f;
    float v1 = (d1 < IN_DIM) ? xr[d1] * dv : 0.0f;
    u32 o = (u32)f2b(v0) | ((u32)f2b(v1) << 16);
    *(u32*)(xs + (size_t)node * KPX + d0) = o;
}

// ---- 96-dim aggregate -> Xa [M_PAD x 128] (dims 96..127 zeroed) ----
__global__ __launch_bounds__(256) void k_agg96(const int* __restrict__ rowptr,
                                               const int* __restrict__ col,
                                               const u16* __restrict__ xs,
                                               const float* __restrict__ dinv,
                                               u16* __restrict__ xa) {
    int node = blockIdx.x * 4 + (threadIdx.x >> 6);
    if (node >= N_NODES) return;
    int lane = threadIdx.x & 63;
    if (lane >= 48) {                    // zero the K-pad region
        *(u32*)(xa + (size_t)node * KPA + lane * 2) = 0;
        return;
    }
    int j = lane * 2;
    u32 v = *(const u32*)(xs + (size_t)node * KPX + j);
    float a0 = lo16(v), a1 = hi16(v);
    int e = rowptr[node], end = rowptr[node + 1];
    for (; e + 4 <= end; e += 4) {
        int s0 = col[e], s1 = col[e + 1], s2 = col[e + 2], s3 = col[e + 3];
        u32 w0 = *(const u32*)(xs + (size_t)s0 * KPX + j);
        u32 w1 = *(const u32*)(xs + (size_t)s1 * KPX + j);
        u32 w2 = *(const u32*)(xs + (size_t)s2 * KPX + j);
        u32 w3 = *(const u32*)(xs + (size_t)s3 * KPX + j);
        a0 += (lo16(w0) + lo16(w1)) + (lo16(w2) + lo16(w3));
        a1 += (hi16(w0) + hi16(w1)) + (hi16(w2) + hi16(w3));
    }
    for (; e < end; ++e) {
        u32 w = *(const u32*)(xs + (size_t)col[e] * KPX + j);
        a0 += lo16(w); a1 += hi16(w);
    }
    float dv = dinv[node];
    u32 o = (u32)f2b(a0 * dv) | ((u32)f2b(a1 * dv) << 16);
    *(u32*)(xa + (size_t)node * KPA + j) = o;
}

// ---- 128x128-tile MFMA GEMM, global_load_lds staging, XOR-swizzled LDS ----
// A: [M_PAD x KP] bf16 (pitch KP), Wt: [256 x KP] bf16. grid (M/128, 256/128).
// MODE 0: Out = dinv[m]*(A@Wt^T).  MODE 1: Out = relu(A@Wt^T + bias).
template<int MODE>
__global__ __launch_bounds__(256) void k_gemm(const u16* __restrict__ A, int KP,
                                              const u16* __restrict__ Wt,
                                              const float* __restrict__ dinv,
                                              const float* __restrict__ bias,
                                              u16* __restrict__ Out) {
    __shared__ __align__(16) u16 As[128 * 64];   // [row][chunk^ (row&7)], chunk=8 elems
    __shared__ __align__(16) u16 Bs[128 * 64];   // [col][chunk^ (col&7)]

    const int tid  = threadIdx.x;
    const int wave = tid >> 6;
    const int lane = tid & 63;
    const int quad = lane >> 4;
    const int lm   = lane & 15;
    const int wr   = wave >> 1;          // wave row (0,1)
    const int wc   = wave & 1;           // wave col (0,1)
    const int m0   = blockIdx.x * 128;
    const int n0   = blockIdx.y * 128;

    f32x4 acc[4][4] = {};

    const int sr = lane >> 3;            // 0..7: row within 8-row segment
    const int sc = lane & 7;             // 0..7: lds chunk slot
    const int gc = sc ^ (sr & 7);        // global chunk for this slot

    for (int kt = 0; kt < KP; kt += 64) {
        __syncthreads();
        #pragma unroll
        for (int i = 0; i < 4; ++i) {
            int s = wave * 4 + i;                    // segment 0..15 (8 rows each)
            int r = s * 8 + sr;
            const u16* ga = A  + (size_t)(m0 + r) * KP + kt + gc * 8;
            const u16* gb = Wt + (size_t)(n0 + r) * KP + kt + gc * 8;
            gl_lds16(ga, As + s * 512);
            gl_lds16(gb, Bs + s * 512);
        }
        __syncthreads();

        #pragma unroll
        for (int st = 0; st < 2; ++st) {
            bf16x8 af[4], bfr[4];
            const int slot = ((st * 4 + quad) ^ (lm & 7)) * 8;
            #pragma unroll
            for (int rt = 0; rt < 4; ++rt)
                af[rt] = *(const bf16x8*)(As + (wr * 64 + rt * 16 + lm) * 64 + slot);
            #pragma unroll
            for (int ct = 0; ct < 4; ++ct)
                bfr[ct] = *(const bf16x8*)(Bs + (wc * 64 + ct * 16 + lm) * 64 + slot);
            #pragma unroll
            for (int rt = 0; rt < 4; ++rt)
                #pragma unroll
                for (int ct = 0; ct < 4; ++ct)
                    acc[rt][ct] = __builtin_amdgcn_mfma_f32_16x16x32_bf16(af[rt], bfr[ct], acc[rt][ct], 0, 0, 0);
        }
    }

    #pragma unroll
    for (int rt = 0; rt < 4; ++rt) {
        #pragma unroll
        for (int reg = 0; reg < 4; ++reg) {
            int m = m0 + wr * 64 + rt * 16 + quad * 4 + reg;
            if (m >= N_NODES) continue;
            float dv = (MODE == 0) ? dinv[m] : 0.0f;
            #pragma unroll
            for (int ct = 0; ct < 4; ++ct) {
                int n = n0 + wc * 64 + ct * 16 + lm;
                float v = acc[rt][ct][reg];
                if (MODE == 0) v *= dv;
                else           v = fmaxf(v + bias[n], 0.0f);
                Out[(size_t)m * HID + n] = f2b(v);
            }
        }
    }
}

// ---- 256-dim aggregate + bias + relu -> bf16 X' (layers 2,3) ----
__global__ __launch_bounds__(256) void k_agg256(const int* __restrict__ rowptr,
                                                const int* __restrict__ col,
                                                const u16* __restrict__ g,
                                                const float* __restrict__ dinv,
                                                const float* __restrict__ bias,
                                                u16* __restrict__ Xout) {
    int node = blockIdx.x * 4 + (threadIdx.x >> 6);
    if (node >= N_NODES) return;
    int lane = threadIdx.x & 63;
    int j = lane * 4;
    const u16* gj = g + j;

    float a0, a1, a2, a3;
    {
        uint2 v = *(const uint2*)(gj + (size_t)node * HID);
        a0 = lo16(v.x); a1 = hi16(v.x); a2 = lo16(v.y); a3 = hi16(v.y);
    }
    int e = rowptr[node], end = rowptr[node + 1];
    for (; e + 4 <= end; e += 4) {
        int s0 = col[e], s1 = col[e + 1], s2 = col[e + 2], s3 = col[e + 3];
        uint2 w0 = *(const uint2*)(gj + (size_t)s0 * HID);
        uint2 w1 = *(const uint2*)(gj + (size_t)s1 * HID);
        uint2 w2 = *(const uint2*)(gj + (size_t)s2 * HID);
        uint2 w3 = *(const uint2*)(gj + (size_t)s3 * HID);
        a0 += (lo16(w0.x) + lo16(w1.x)) + (lo16(w2.x) + lo16(w3.x));
        a1 += (hi16(w0.x) + hi16(w1.x)) + (hi16(w2.x) + hi16(w3.x));
        a2 += (lo16(w0.y) + lo16(w1.y)) + (lo16(w2.y) + lo16(w3.y));
        a3 += (hi16(w0.y) + hi16(w1.y)) + (hi16(w2.y) + hi16(w3.y));
    }
    for (; e < end; ++e) {
        int s = col[e];
        uint2 w = *(const uint2*)(gj + (size_t)s * HID);
        a0 += lo16(w.x); a1 += hi16(w.x); a2 += lo16(w.y); a3 += hi16(w.y);
    }
    float dv = dinv[node];
    float4 bb = *(const float4*)(bias + j);
    a0 = fmaxf(fmaf(a0, dv, bb.x), 0.0f);
    a1 = fmaxf(fmaf(a1, dv, bb.y), 0.0f);
    a2 = fmaxf(fmaf(a2, dv, bb.z), 0.0f);
    a3 = fmaxf(fmaf(a3, dv, bb.w), 0.0f);
    uint2 o;
    o.x = (u32)f2b(a0) | ((u32)f2b(a1) << 16);
    o.y = (u32)f2b(a2) | ((u32)f2b(a3) << 16);
    *(uint2*)(Xout + (size_t)node * HID + j) = o;
}

// ---- g4 = dinv .* (X4 @ W4l)  [N x 2] f32. wave/node, shfl reduce ----
__global__ __launch_bounds__(256) void k_gemm2col(const u16* __restrict__ X,
                                                  const float* __restrict__ W4l,
                                                  const float* __restrict__ dinv,
                                                  float* __restrict__ g4) {
    __shared__ float2 sW[HID];
    int tid = threadIdx.x;
    sW[tid] = *(const float2*)(W4l + tid * 2);
    __syncthreads();

    int node = blockIdx.x * 4 + (tid >> 6);
    if (node >= N_NODES) return;
    int lane = tid & 63;
    uint2 v = *(const uint2*)(X + (size_t)node * HID + lane * 4);
    float x0 = lo16(v.x), x1 = hi16(v.x), x2 = lo16(v.y), x3 = hi16(v.y);
    float2 w0 = sW[lane * 4 + 0], w1 = sW[lane * 4 + 1];
    float2 w2 = sW[lane * 4 + 2], w3 = sW[lane * 4 + 3];
    float s0 = x0 * w0.x + x1 * w1.x + x2 * w2.x + x3 * w3.x;
    float s1 = x0 * w0.y + x1 * w1.y + x2 * w2.y + x3 * w3.y;
    #pragma unroll
    for (int off = 32; off >= 1; off >>= 1) {
        s0 += __shfl_down(s0, off);
        s1 += __shfl_down(s1, off);
    }
    if (lane == 0) {
        float dv = dinv[node];
        *(float2*)(g4 + (size_t)node * 2) = make_float2(s0 * dv, s1 * dv);
    }
}

// ---- 2-dim aggregate ----
__global__ void k_agg2(const int* __restrict__ rowptr, const int* __restrict__ col,
                       const float* __restrict__ g4, const float* __restrict__ dinv,
                       float* __restrict__ h4) {
    int node = blockIdx.x * blockDim.x + threadIdx.x;
    if (node >= N_NODES) return;
    float2 a = *(const float2*)(g4 + (size_t)node * 2);
    int e = rowptr[node], end = rowptr[node + 1];
    for (; e < end; ++e) {
        float2 w = *(const float2*)(g4 + (size_t)col[e] * 2);
        a.x += w.x; a.y += w.y;
    }
    float dv = dinv[node];
    *(float2*)(h4 + (size_t)node * 2) = make_float2(a.x * dv, a.y * dv);
}

// ---- per-graph mean of h4 + c4 -> out [NG x 2] f32 ----
__global__ __launch_bounds__(256) void k_pool2(const float* __restrict__ h4,
                                               const int* __restrict__ gptr,
                                               const float* __restrict__ c4,
                                               float* __restrict__ out) {
    int gph = blockIdx.x * 4 + (threadIdx.x >> 6);
    if (gph >= NG) return;
    int lane = threadIdx.x & 63;
    int b = gptr[gph], e = gptr[gph + 1];
    float s0 = 0.0f, s1 = 0.0f;
    for (int n = b + lane; n < e; n += 64) {
        float2 v = *(const float2*)(h4 + (size_t)n * 2);
        s0 += v.x; s1 += v.y;
    }
    #pragma unroll
    for (int off = 32; off >= 1; off >>= 1) {
        s0 += __shfl_down(s0, off);
        s1 += __shfl_down(s1, off);
    }
    if (lane == 0) {
        float inv = 1.0f / fmaxf((float)(e - b), 1.0f);
        out[gph * 2 + 0] = s0 * inv + c4[0];
        out[gph * 2 + 1] = s1 * inv + c4[1];
    }
}

extern "C" void kernel_launch(void* const* d_in, const int* in_sizes, int n_in,
                              void* d_out, int out_size, void* d_ws, size_t ws_size,
                              hipStream_t stream) {
    const float* x   = (const float*)d_in[0];
    const int* ei    = (const int*)d_in[1];
    const int* src   = ei;
    const int* dst   = ei + N_EDGES;
    const int* batch = (const int*)d_in[2];
    const float* W1 = (const float*)d_in[3];  const float* b1 = (const float*)d_in[4];
    const float* W2 = (const float*)d_in[5];  const float* b2 = (const float*)d_in[6];
    const float* W3 = (const float*)d_in[7];  const float* b3 = (const float*)d_in[8];
    const float* W4 = (const float*)d_in[9];  const float* b4 = (const float*)d_in[10];
    const float* Wl = (const float*)d_in[11]; const float* bl = (const float*)d_in[12];
    float* out = (float*)d_out;

    // ---- workspace layout ----
    char* p = (char*)d_ws;
    auto take = [&](size_t bytes) { char* r = p; p += (bytes + 255) & ~(size_t)255; return r; };
    size_t zbytes = (size_t)(N_NODES + N_NODES) * 4;   // deg | fill
    int*   deg  = (int*)take(zbytes);
    int*   fill = deg + N_NODES;
    float* dinv = (float*)take((size_t)N_NODES * sizeof(float));
    int* rowptr = (int*)take((size_t)(N_NODES + 1) * sizeof(int));
    int* col    = (int*)take((size_t)N_EDGES * sizeof(int));
    int* bsum   = (int*)take((size_t)SCAN_B * sizeof(int));
    int* boff   = (int*)take((size_t)SCAN_B * sizeof(int));
    int* gptr   = (int*)take((size_t)(NG + 1) * sizeof(int));
    float* W4l  = (float*)take((size_t)HID * 2 * sizeof(float));
    float* c4   = (float*)take(2 * sizeof(float));
    float* g4   = (float*)take((size_t)N_NODES * 2 * sizeof(float));
    float* h4   = (float*)take((size_t)N_NODES * 2 * sizeof(float));
    u16* Wt1 = (u16*)take((size_t)HID * KPA * 2);
    u16* Wt2 = (u16*)take((size_t)HID * HID * 2);
    u16* Wt3 = (u16*)take((size_t)HID * HID * 2);
    u16* Xs  = (u16*)take((size_t)N_NODES * KPX * 2);
    u16* Xa  = (u16*)take((size_t)M_PAD * KPA * 2);    // padded rows for 128-tile staging
    u16* Gbuf = (u16*)take((size_t)N_NODES * HID * 2);
    u16* Xbuf = (u16*)take((size_t)M_PAD * HID * 2);   // padded rows for 128-tile staging

    hipMemsetAsync(deg, 0, zbytes, stream);

    // CSR build + norms + prep
    k_deg<<<(N_EDGES + 255) / 256, 256, 0, stream>>>(dst, deg);
    k_scan_local<<<SCAN_B, 256, 0, stream>>>(deg, rowptr, bsum, dinv);
    k_scan_bsum<<<1, 512, 0, stream>>>(bsum, boff);
    k_scan_add<<<SCAN_B, 256, 0, stream>>>(rowptr, boff);
    k_fill<<<(N_EDGES + 255) / 256, 256, 0, stream>>>(src, dst, rowptr, fill, col);
    k_prep<<<KPA + 2 * HID + 1 + (NG + 256) / 256, 256, 0, stream>>>(
        W1, W2, W3, W4, Wl, b4, bl, batch, Wt1, Wt2, Wt3, W4l, c4, gptr);

    const int nb4 = (N_NODES + 3) / 4;
    const dim3 gemm_grid(M_PAD / 128, HID / 128);

    // layer 1: aggregate-first in input space, bias+relu fused in GEMM
    k_pad_scale<<<nb4, 256, 0, stream>>>(x, dinv, Xs);
    k_agg96<<<nb4, 256, 0, stream>>>(rowptr, col, Xs, dinv, Xa);
    k_gemm<1><<<gemm_grid, 256, 0, stream>>>(Xa, KPA, Wt1, dinv, b1, Xbuf);
    // layer 2
    k_gemm<0><<<gemm_grid, 256, 0, stream>>>(Xbuf, HID, Wt2, dinv, b2, Gbuf);
    k_agg256<<<nb4, 256, 0, stream>>>(rowptr, col, Gbuf, dinv, b2, Xbuf);
    // layer 3
    k_gemm<0><<<gemm_grid, 256, 0, stream>>>(Xbuf, HID, Wt3, dinv, b3, Gbuf);
    k_agg256<<<nb4, 256, 0, stream>>>(rowptr, col, Gbuf, dinv, b3, Xbuf);
    // layer 4 + head, collapsed to 2 dims
    k_gemm2col<<<nb4, 256, 0, stream>>>(Xbuf, W4l, dinv, g4);
    k_agg2<<<(N_NODES + 255) / 256, 256, 0, stream>>>(rowptr, col, g4, dinv, h4);
    k_pool2<<<(NG + 3) / 4, 256, 0, stream>>>(h4, gptr, c4, out);
}

// Round 7
// 398.506 us; speedup vs baseline: 4.6321x; 1.0715x over previous
//
#include <hip/hip_runtime.h>
#include <hip/hip_bf16.h>

#define N_NODES 100000
#define M_PAD   100096   // 782 * 128, so 128-row GEMM tiles never read OOB
#define N_EDGES 400000
#define IN_DIM  69
#define KPX     96       // Xs pitch (gather space for layer-1 aggregate)
#define KPA     128      // Xa pitch (layer-1 GEMM K, padded to BK multiple)
#define HID     256
#define NG      4096
#define SCAN_B  391      // ceil(N_NODES / 256)
#define FILL_B  1563     // ceil(N_EDGES / 256)

typedef __attribute__((ext_vector_type(8))) short bf16x8;
typedef __attribute__((ext_vector_type(4))) float f32x4;
typedef unsigned short u16;
typedef unsigned int   u32;

__device__ __forceinline__ float b2f(u16 v) {
    u32 x = ((u32)v) << 16;
    return __builtin_bit_cast(float, x);
}
__device__ __forceinline__ u16 f2b(float f) {
    u32 x = __builtin_bit_cast(u32, f);
    u32 r = (x + 0x7FFF + ((x >> 16) & 1)) >> 16;   // RNE
    return (u16)r;
}
__device__ __forceinline__ float lo16(u32 v) { return b2f((u16)(v & 0xffff)); }
__device__ __forceinline__ float hi16(u32 v) { return b2f((u16)(v >> 16)); }

__device__ __forceinline__ void acc8(float* a, uint4 w, float m) {
    a[0] = fmaf(m, lo16(w.x), a[0]); a[1] = fmaf(m, hi16(w.x), a[1]);
    a[2] = fmaf(m, lo16(w.y), a[2]); a[3] = fmaf(m, hi16(w.y), a[3]);
    a[4] = fmaf(m, lo16(w.z), a[4]); a[5] = fmaf(m, hi16(w.z), a[5]);
    a[6] = fmaf(m, lo16(w.w), a[6]); a[7] = fmaf(m, hi16(w.w), a[7]);
}
__device__ __forceinline__ void acc4(float* a, uint2 w, float m) {
    a[0] = fmaf(m, lo16(w.x), a[0]); a[1] = fmaf(m, hi16(w.x), a[1]);
    a[2] = fmaf(m, lo16(w.y), a[2]); a[3] = fmaf(m, hi16(w.y), a[3]);
}

// async global->LDS, 16B per lane; LDS dest = wave-uniform base + lane*16
__device__ __forceinline__ void gl_lds16(const u16* g, u16* l) {
    __builtin_amdgcn_global_load_lds(
        (const __attribute__((address_space(1))) void*)g,
        (__attribute__((address_space(3))) void*)l, 16, 0, 0);
}

// ---- in-degree count (int) ----
__global__ void k_deg(const int* __restrict__ dst, int* __restrict__ deg) {
    int e = blockIdx.x * blockDim.x + threadIdx.x;
    if (e < N_EDGES) atomicAdd(&deg[dst[e]], 1);
}

// ---- local scan + dinv fused ----
__global__ void k_scan_local(const int* __restrict__ deg, int* __restrict__ rowptr,
                             int* __restrict__ bsum, float* __restrict__ dinv) {
    __shared__ int s[256];
    int tid = threadIdx.x;
    int i = blockIdx.x * 256 + tid;
    int v = (i < N_NODES) ? deg[i] : 0;
    if (i < N_NODES) dinv[i] = rsqrtf((float)v + 1.0f);
    s[tid] = v;
    __syncthreads();
    #pragma unroll
    for (int off = 1; off < 256; off <<= 1) {
        int t = 0;
        if (tid >= off) t = s[tid - off];
        __syncthreads();
        if (tid >= off) s[tid] += t;
        __syncthreads();
    }
    if (i < N_NODES) rowptr[i] = s[tid] - v;          // exclusive
    if (tid == 255) bsum[blockIdx.x] = s[255];        // block total
}

__global__ void k_scan_bsum(int* __restrict__ bsum, int* __restrict__ boff) {
    __shared__ int s[512];
    int tid = threadIdx.x;
    int v = (tid < SCAN_B) ? bsum[tid] : 0;
    s[tid] = v;
    __syncthreads();
    #pragma unroll
    for (int off = 1; off < 512; off <<= 1) {
        int t = 0;
        if (tid >= off) t = s[tid - off];
        __syncthreads();
        if (tid >= off) s[tid] += t;
        __syncthreads();
    }
    if (tid < SCAN_B) boff[tid] = s[tid] - v;         // exclusive
}

__global__ void k_scan_add(int* __restrict__ rowptr, const int* __restrict__ boff) {
    int i = blockIdx.x * 256 + threadIdx.x;
    if (i < N_NODES) rowptr[i] += boff[blockIdx.x];
    if (i == 0) rowptr[N_NODES] = N_EDGES;
}

// ---- CSR fill + Xs = dinv.*x pad/scale, merged (both post-scan) ----
__global__ __launch_bounds__(256) void k_fill_pad(const int* __restrict__ src,
                       const int* __restrict__ dst,
                       const int* __restrict__ rowptr, int* __restrict__ fill,
                       int* __restrict__ col,
                       const float* __restrict__ x, const float* __restrict__ dinv,
                       u16* __restrict__ xs) {
    if (blockIdx.x < FILL_B) {
        int e = blockIdx.x * 256 + threadIdx.x;
        if (e < N_EDGES) {
            int d = dst[e];
            int pos = rowptr[d] + atomicAdd(&fill[d], 1);
            col[pos] = src[e];
        }
    } else {
        int node = (blockIdx.x - FILL_B) * 4 + (threadIdx.x >> 6);
        if (node >= N_NODES) return;
        int lane = threadIdx.x & 63;
        if (lane >= 48) return;
        int d0 = lane * 2, d1 = lane * 2 + 1;
        float dv = dinv[node];
        const float* xr = x + (size_t)node * IN_DIM;
        float v0 = (d0 < IN_DIM) ? xr[d0] * dv : 0.0f;
        float v1 = (d1 < IN_DIM) ? xr[d1] * dv : 0.0f;
        u32 o = (u32)f2b(v0) | ((u32)f2b(v1) << 16);
        *(u32*)(xs + (size_t)node * KPX + d0) = o;
    }
}

// ---- merged prep: W1/W2/W3 transpose->bf16, W4@Wl fold, gptr search ----
__global__ void k_prep(const float* __restrict__ W1, const float* __restrict__ W2,
                       const float* __restrict__ W3, const float* __restrict__ W4,
                       const float* __restrict__ Wl, const float* __restrict__ b4,
                       const float* __restrict__ bl, const int* __restrict__ batch,
                       u16* __restrict__ Wt1, u16* __restrict__ Wt2, u16* __restrict__ Wt3,
                       float* __restrict__ W4l, float* __restrict__ c4, int* __restrict__ gptr) {
    int b = blockIdx.x;
    int t = threadIdx.x;
    if (b < KPA) {                       // Wt1 [256 x 128], zero-padded K
        Wt1[(size_t)t * KPA + b] = (b < IN_DIM) ? f2b(W1[(size_t)b * HID + t]) : (u16)0;
    } else if (b < KPA + HID) {          // Wt2 [256 x 256]
        int k = b - KPA;
        Wt2[(size_t)t * HID + k] = f2b(W2[(size_t)k * HID + t]);
    } else if (b < KPA + 2 * HID) {      // Wt3
        int k = b - KPA - HID;
        Wt3[(size_t)t * HID + k] = f2b(W3[(size_t)k * HID + t]);
    } else if (b == KPA + 2 * HID) {     // W4l = W4 @ Wl ; c4 = b4 @ Wl + bl
        float s0 = 0.0f, s1 = 0.0f;
        const float* wr = W4 + (size_t)t * HID;
        for (int j = 0; j < HID; ++j) {
            float w = wr[j];
            s0 += w * Wl[j * 2 + 0];
            s1 += w * Wl[j * 2 + 1];
        }
        W4l[t * 2 + 0] = s0;
        W4l[t * 2 + 1] = s1;
        if (t < 2) {
            float s = bl[t];
            for (int j = 0; j < HID; ++j) s += b4[j] * Wl[j * 2 + t];
            c4[t] = s;
        }
    } else {                             // gptr: lower_bound(batch, g)
        int g = (b - (KPA + 2 * HID + 1)) * 256 + t;
        if (g > NG) return;
        if (g == NG) { gptr[NG] = N_NODES; return; }
        int lo = 0, hi = N_NODES;
        while (lo < hi) {
            int mid = (lo + hi) >> 1;
            if (batch[mid] < g) lo = mid + 1; else hi = mid;
        }
        gptr[g] = lo;
    }
}

// ---- 96-dim aggregate -> Xa [M_PAD x 128]; 32 lanes/node, predicated unroll-4 ----
__global__ __launch_bounds__(256) void k_agg96(const int* __restrict__ rowptr,
                                               const int* __restrict__ col,
                                               const u16* __restrict__ xs,
                                               const float* __restrict__ dinv,
                                               u16* __restrict__ xa) {
    int node = blockIdx.x * 8 + (threadIdx.x >> 5);
    if (node >= N_NODES) return;
    int l = threadIdx.x & 31;
    int j = l * 4;
    if (l >= 24) {                       // K-pad region (dims 96..127) -> zero
        *(uint2*)(xa + (size_t)node * KPA + j) = make_uint2(0, 0);
        return;
    }
    const u16* xj = xs + j;
    float a[4];
    {
        uint2 v = *(const uint2*)(xj + (size_t)node * KPX);
        a[0] = lo16(v.x); a[1] = hi16(v.x); a[2] = lo16(v.y); a[3] = hi16(v.y);
    }
    int e = rowptr[node], end = rowptr[node + 1];
    for (; e < end; e += 4) {
        int i1 = (e + 1 < end) ? e + 1 : e;
        int i2 = (e + 2 < end) ? e + 2 : e;
        int i3 = (e + 3 < end) ? e + 3 : e;
        int s0 = col[e], s1 = col[i1], s2 = col[i2], s3 = col[i3];
        uint2 w0 = *(const uint2*)(xj + (size_t)s0 * KPX);
        uint2 w1 = *(const uint2*)(xj + (size_t)s1 * KPX);
        uint2 w2 = *(const uint2*)(xj + (size_t)s2 * KPX);
        uint2 w3 = *(const uint2*)(xj + (size_t)s3 * KPX);
        float m1 = (e + 1 < end) ? 1.0f : 0.0f;
        float m2 = (e + 2 < end) ? 1.0f : 0.0f;
        float m3 = (e + 3 < end) ? 1.0f : 0.0f;
        acc4(a, w0, 1.0f); acc4(a, w1, m1); acc4(a, w2, m2); acc4(a, w3, m3);
    }
    float dv = dinv[node];
    uint2 o;
    o.x = (u32)f2b(a[0] * dv) | ((u32)f2b(a[1] * dv) << 16);
    o.y = (u32)f2b(a[2] * dv) | ((u32)f2b(a[3] * dv) << 16);
    *(uint2*)(xa + (size_t)node * KPA + j) = o;
}

// ---- 128x128-tile MFMA GEMM, global_load_lds staging, XOR-swizzled LDS ----
// MODE 0: Out = dinv[m]*(A@Wt^T).  MODE 1: Out = relu(A@Wt^T + bias).
template<int MODE>
__global__ __launch_bounds__(256) void k_gemm(const u16* __restrict__ A, int KP,
                                              const u16* __restrict__ Wt,
                                              const float* __restrict__ dinv,
                                              const float* __restrict__ bias,
                                              u16* __restrict__ Out) {
    __shared__ __align__(16) u16 As[128 * 64];   // [row][chunk ^ (row&7)]
    __shared__ __align__(16) u16 Bs[128 * 64];

    const int tid  = threadIdx.x;
    const int wave = tid >> 6;
    const int lane = tid & 63;
    const int quad = lane >> 4;
    const int lm   = lane & 15;
    const int wr   = wave >> 1;
    const int wc   = wave & 1;
    const int m0   = blockIdx.x * 128;
    const int n0   = blockIdx.y * 128;

    f32x4 acc[4][4] = {};

    const int sr = lane >> 3;
    const int sc = lane & 7;
    const int gc = sc ^ (sr & 7);

    for (int kt = 0; kt < KP; kt += 64) {
        __syncthreads();
        #pragma unroll
        for (int i = 0; i < 4; ++i) {
            int s = wave * 4 + i;
            int r = s * 8 + sr;
            const u16* ga = A  + (size_t)(m0 + r) * KP + kt + gc * 8;
            const u16* gb = Wt + (size_t)(n0 + r) * KP + kt + gc * 8;
            gl_lds16(ga, As + s * 512);
            gl_lds16(gb, Bs + s * 512);
        }
        __syncthreads();

        #pragma unroll
        for (int st = 0; st < 2; ++st) {
            bf16x8 af[4], bfr[4];
            const int slot = ((st * 4 + quad) ^ (lm & 7)) * 8;
            #pragma unroll
            for (int rt = 0; rt < 4; ++rt)
                af[rt] = *(const bf16x8*)(As + (wr * 64 + rt * 16 + lm) * 64 + slot);
            #pragma unroll
            for (int ct = 0; ct < 4; ++ct)
                bfr[ct] = *(const bf16x8*)(Bs + (wc * 64 + ct * 16 + lm) * 64 + slot);
            #pragma unroll
            for (int rt = 0; rt < 4; ++rt)
                #pragma unroll
                for (int ct = 0; ct < 4; ++ct)
                    acc[rt][ct] = __builtin_amdgcn_mfma_f32_16x16x32_bf16(af[rt], bfr[ct], acc[rt][ct], 0, 0, 0);
        }
    }

    #pragma unroll
    for (int rt = 0; rt < 4; ++rt) {
        #pragma unroll
        for (int reg = 0; reg < 4; ++reg) {
            int m = m0 + wr * 64 + rt * 16 + quad * 4 + reg;
            if (m >= N_NODES) continue;
            float dv = (MODE == 0) ? dinv[m] : 0.0f;
            #pragma unroll
            for (int ct = 0; ct < 4; ++ct) {
                int n = n0 + wc * 64 + ct * 16 + lm;
                float v = acc[rt][ct][reg];
                if (MODE == 0) v *= dv;
                else           v = fmaxf(v + bias[n], 0.0f);
                Out[(size_t)m * HID + n] = f2b(v);
            }
        }
    }
}

// ---- 256-dim aggregate + bias + relu; 32 lanes/node, 16B loads, predicated unroll-4 ----
__global__ __launch_bounds__(256) void k_agg256(const int* __restrict__ rowptr,
                                                const int* __restrict__ col,
                                                const u16* __restrict__ g,
                                                const float* __restrict__ dinv,
                                                const float* __restrict__ bias,
                                                u16* __restrict__ Xout) {
    int node = blockIdx.x * 8 + (threadIdx.x >> 5);
    if (node >= N_NODES) return;
    int l = threadIdx.x & 31;
    int j = l * 8;
    const u16* gj = g + j;

    float a[8];
    {
        uint4 v = *(const uint4*)(gj + (size_t)node * HID);
        a[0] = lo16(v.x); a[1] = hi16(v.x); a[2] = lo16(v.y); a[3] = hi16(v.y);
        a[4] = lo16(v.z); a[5] = hi16(v.z); a[6] = lo16(v.w); a[7] = hi16(v.w);
    }
    int e = rowptr[node], end = rowptr[node + 1];
    for (; e < end; e += 4) {
        int i1 = (e + 1 < end) ? e + 1 : e;
        int i2 = (e + 2 < end) ? e + 2 : e;
        int i3 = (e + 3 < end) ? e + 3 : e;
        int s0 = col[e], s1 = col[i1], s2 = col[i2], s3 = col[i3];
        uint4 w0 = *(const uint4*)(gj + (size_t)s0 * HID);
        uint4 w1 = *(const uint4*)(gj + (size_t)s1 * HID);
        uint4 w2 = *(const uint4*)(gj + (size_t)s2 * HID);
        uint4 w3 = *(const uint4*)(gj + (size_t)s3 * HID);
        float m1 = (e + 1 < end) ? 1.0f : 0.0f;
        float m2 = (e + 2 < end) ? 1.0f : 0.0f;
        float m3 = (e + 3 < end) ? 1.0f : 0.0f;
        acc8(a, w0, 1.0f); acc8(a, w1, m1); acc8(a, w2, m2); acc8(a, w3, m3);
    }
    float dv = dinv[node];
    float4 b0 = *(const float4*)(bias + j);
    float4 b1 = *(const float4*)(bias + j + 4);
    float r0 = fmaxf(fmaf(a[0], dv, b0.x), 0.0f);
    float r1 = fmaxf(fmaf(a[1], dv, b0.y), 0.0f);
    float r2 = fmaxf(fmaf(a[2], dv, b0.z), 0.0f);
    float r3 = fmaxf(fmaf(a[3], dv, b0.w), 0.0f);
    float r4 = fmaxf(fmaf(a[4], dv, b1.x), 0.0f);
    float r5 = fmaxf(fmaf(a[5], dv, b1.y), 0.0f);
    float r6 = fmaxf(fmaf(a[6], dv, b1.z), 0.0f);
    float r7 = fmaxf(fmaf(a[7], dv, b1.w), 0.0f);
    uint4 o;
    o.x = (u32)f2b(r0) | ((u32)f2b(r1) << 16);
    o.y = (u32)f2b(r2) | ((u32)f2b(r3) << 16);
    o.z = (u32)f2b(r4) | ((u32)f2b(r5) << 16);
    o.w = (u32)f2b(r6) | ((u32)f2b(r7) << 16);
    *(uint4*)(Xout + (size_t)node * HID + j) = o;
}

// ---- g4 = dinv .* (X4 @ W4l)  [N x 2] f32. wave/node, shfl reduce ----
__global__ __launch_bounds__(256) void k_gemm2col(const u16* __restrict__ X,
                                                  const float* __restrict__ W4l,
                                                  const float* __restrict__ dinv,
                                                  float* __restrict__ g4) {
    __shared__ float2 sW[HID];
    int tid = threadIdx.x;
    sW[tid] = *(const float2*)(W4l + tid * 2);
    __syncthreads();

    int node = blockIdx.x * 4 + (tid >> 6);
    if (node >= N_NODES) return;
    int lane = tid & 63;
    uint2 v = *(const uint2*)(X + (size_t)node * HID + lane * 4);
    float x0 = lo16(v.x), x1 = hi16(v.x), x2 = lo16(v.y), x3 = hi16(v.y);
    float2 w0 = sW[lane * 4 + 0], w1 = sW[lane * 4 + 1];
    float2 w2 = sW[lane * 4 + 2], w3 = sW[lane * 4 + 3];
    float s0 = x0 * w0.x + x1 * w1.x + x2 * w2.x + x3 * w3.x;
    float s1 = x0 * w0.y + x1 * w1.y + x2 * w2.y + x3 * w3.y;
    #pragma unroll
    for (int off = 32; off >= 1; off >>= 1) {
        s0 += __shfl_down(s0, off);
        s1 += __shfl_down(s1, off);
    }
    if (lane == 0) {
        float dv = dinv[node];
        *(float2*)(g4 + (size_t)node * 2) = make_float2(s0 * dv, s1 * dv);
    }
}

// ---- 2-dim aggregate ----
__global__ void k_agg2(const int* __restrict__ rowptr, const int* __restrict__ col,
                       const float* __restrict__ g4, const float* __restrict__ dinv,
                       float* __restrict__ h4) {
    int node = blockIdx.x * blockDim.x + threadIdx.x;
    if (node >= N_NODES) return;
    float2 a = *(const float2*)(g4 + (size_t)node * 2);
    int e = rowptr[node], end = rowptr[node + 1];
    for (; e < end; ++e) {
        float2 w = *(const float2*)(g4 + (size_t)col[e] * 2);
        a.x += w.x; a.y += w.y;
    }
    float dv = dinv[node];
    *(float2*)(h4 + (size_t)node * 2) = make_float2(a.x * dv, a.y * dv);
}

// ---- per-graph mean of h4 + c4 -> out [NG x 2] f32 ----
__global__ __launch_bounds__(256) void k_pool2(const float* __restrict__ h4,
                                               const int* __restrict__ gptr,
                                               const float* __restrict__ c4,
                                               float* __restrict__ out) {
    int gph = blockIdx.x * 4 + (threadIdx.x >> 6);
    if (gph >= NG) return;
    int lane = threadIdx.x & 63;
    int b = gptr[gph], e = gptr[gph + 1];
    float s0 = 0.0f, s1 = 0.0f;
    for (int n = b + lane; n < e; n += 64) {
        float2 v = *(const float2*)(h4 + (size_t)n * 2);
        s0 += v.x; s1 += v.y;
    }
    #pragma unroll
    for (int off = 32; off >= 1; off >>= 1) {
        s0 += __shfl_down(s0, off);
        s1 += __shfl_down(s1, off);
    }
    if (lane == 0) {
        float inv = 1.0f / fmaxf((float)(e - b), 1.0f);
        out[gph * 2 + 0] = s0 * inv + c4[0];
        out[gph * 2 + 1] = s1 * inv + c4[1];
    }
}

extern "C" void kernel_launch(void* const* d_in, const int* in_sizes, int n_in,
                              void* d_out, int out_size, void* d_ws, size_t ws_size,
                              hipStream_t stream) {
    const float* x   = (const float*)d_in[0];
    const int* ei    = (const int*)d_in[1];
    const int* src   = ei;
    const int* dst   = ei + N_EDGES;
    const int* batch = (const int*)d_in[2];
    const float* W1 = (const float*)d_in[3];  const float* b1 = (const float*)d_in[4];
    const float* W2 = (const float*)d_in[5];  const float* b2 = (const float*)d_in[6];
    const float* W3 = (const float*)d_in[7];  const float* b3 = (const float*)d_in[8];
    const float* W4 = (const float*)d_in[9];  const float* b4 = (const float*)d_in[10];
    const float* Wl = (const float*)d_in[11]; const float* bl = (const float*)d_in[12];
    float* out = (float*)d_out;

    // ---- workspace layout ----
    char* p = (char*)d_ws;
    auto take = [&](size_t bytes) { char* r = p; p += (bytes + 255) & ~(size_t)255; return r; };
    size_t zbytes = (size_t)(N_NODES + N_NODES) * 4;   // deg | fill
    int*   deg  = (int*)take(zbytes);
    int*   fill = deg + N_NODES;
    float* dinv = (float*)take((size_t)N_NODES * sizeof(float));
    int* rowptr = (int*)take((size_t)(N_NODES + 1) * sizeof(int));
    int* col    = (int*)take((size_t)N_EDGES * sizeof(int));
    int* bsum   = (int*)take((size_t)SCAN_B * sizeof(int));
    int* boff   = (int*)take((size_t)SCAN_B * sizeof(int));
    int* gptr   = (int*)take((size_t)(NG + 1) * sizeof(int));
    float* W4l  = (float*)take((size_t)HID * 2 * sizeof(float));
    float* c4   = (float*)take(2 * sizeof(float));
    float* g4   = (float*)take((size_t)N_NODES * 2 * sizeof(float));
    float* h4   = (float*)take((size_t)N_NODES * 2 * sizeof(float));
    u16* Wt1 = (u16*)take((size_t)HID * KPA * 2);
    u16* Wt2 = (u16*)take((size_t)HID * HID * 2);
    u16* Wt3 = (u16*)take((size_t)HID * HID * 2);
    u16* Xs  = (u16*)take((size_t)N_NODES * KPX * 2);
    u16* Xa  = (u16*)take((size_t)M_PAD * KPA * 2);    // padded rows for 128-tile staging
    u16* Gbuf = (u16*)take((size_t)N_NODES * HID * 2);
    u16* Xbuf = (u16*)take((size_t)M_PAD * HID * 2);   // padded rows for 128-tile staging

    hipMemsetAsync(deg, 0, zbytes, stream);

    // CSR build + norms + prep
    k_deg<<<(N_EDGES + 255) / 256, 256, 0, stream>>>(dst, deg);
    k_scan_local<<<SCAN_B, 256, 0, stream>>>(deg, rowptr, bsum, dinv);
    k_scan_bsum<<<1, 512, 0, stream>>>(bsum, boff);
    k_scan_add<<<SCAN_B, 256, 0, stream>>>(rowptr, boff);
    k_fill_pad<<<FILL_B + (N_NODES + 3) / 4, 256, 0, stream>>>(src, dst, rowptr, fill, col,
                                                               x, dinv, Xs);
    k_prep<<<KPA + 2 * HID + 1 + (NG + 256) / 256, 256, 0, stream>>>(
        W1, W2, W3, W4, Wl, b4, bl, batch, Wt1, Wt2, Wt3, W4l, c4, gptr);

    const int nb8 = (N_NODES + 7) / 8;
    const dim3 gemm_grid(M_PAD / 128, HID / 128);

    // layer 1: aggregate-first in input space, bias+relu fused in GEMM
    k_agg96<<<nb8, 256, 0, stream>>>(rowptr, col, Xs, dinv, Xa);
    k_gemm<1><<<gemm_grid, 256, 0, stream>>>(Xa, KPA, Wt1, dinv, b1, Xbuf);
    // layer 2
    k_gemm<0><<<gemm_grid, 256, 0, stream>>>(Xbuf, HID, Wt2, dinv, b2, Gbuf);
    k_agg256<<<nb8, 256, 0, stream>>>(rowptr, col, Gbuf, dinv, b2, Xbuf);
    // layer 3
    k_gemm<0><<<gemm_grid, 256, 0, stream>>>(Xbuf, HID, Wt3, dinv, b3, Gbuf);
    k_agg256<<<nb8, 256, 0, stream>>>(rowptr, col, Gbuf, dinv, b3, Xbuf);
    // layer 4 + head, collapsed to 2 dims
    k_gemm2col<<<(N_NODES + 3) / 4, 256, 0, stream>>>(Xbuf, W4l, dinv, g4);
    k_agg2<<<(N_NODES + 255) / 256, 256, 0, stream>>>(rowptr, col, g4, dinv, h4);
    k_pool2<<<(NG + 3) / 4, 256, 0, stream>>>(h4, gptr, c4, out);
}

// Round 8
// 377.019 us; speedup vs baseline: 4.8960x; 1.0570x over previous
//
#include <hip/hip_runtime.h>
#include <hip/hip_bf16.h>

#define N_NODES 100000
#define M_PAD   100096   // 782 * 128, so 128-row GEMM tiles never read OOB
#define N_EDGES 400000
#define IN_DIM  69
#define KPX     96       // Xs pitch (gather space for layer-1 aggregate)
#define KPA     128      // Xa pitch (layer-1 GEMM K, padded to BK multiple)
#define HID     256
#define NG      4096
#define SCAN_B  391      // ceil(N_NODES / 256)
#define FILL_B  1563     // ceil(N_EDGES / 256)

typedef __attribute__((ext_vector_type(8))) short bf16x8;
typedef __attribute__((ext_vector_type(4))) float f32x4;
typedef unsigned short u16;
typedef unsigned int   u32;

__device__ __forceinline__ float b2f(u16 v) {
    u32 x = ((u32)v) << 16;
    return __builtin_bit_cast(float, x);
}
__device__ __forceinline__ u16 f2b(float f) {
    u32 x = __builtin_bit_cast(u32, f);
    u32 r = (x + 0x7FFF + ((x >> 16) & 1)) >> 16;   // RNE
    return (u16)r;
}
__device__ __forceinline__ float lo16(u32 v) { return b2f((u16)(v & 0xffff)); }
__device__ __forceinline__ float hi16(u32 v) { return b2f((u16)(v >> 16)); }

__device__ __forceinline__ void acc8(float* a, uint4 w, float m) {
    a[0] = fmaf(m, lo16(w.x), a[0]); a[1] = fmaf(m, hi16(w.x), a[1]);
    a[2] = fmaf(m, lo16(w.y), a[2]); a[3] = fmaf(m, hi16(w.y), a[3]);
    a[4] = fmaf(m, lo16(w.z), a[4]); a[5] = fmaf(m, hi16(w.z), a[5]);
    a[6] = fmaf(m, lo16(w.w), a[6]); a[7] = fmaf(m, hi16(w.w), a[7]);
}
__device__ __forceinline__ void acc4(float* a, uint2 w, float m) {
    a[0] = fmaf(m, lo16(w.x), a[0]); a[1] = fmaf(m, hi16(w.x), a[1]);
    a[2] = fmaf(m, lo16(w.y), a[2]); a[3] = fmaf(m, hi16(w.y), a[3]);
}

// async global->LDS, 16B per lane; LDS dest = wave-uniform base + lane*16
__device__ __forceinline__ void gl_lds16(const u16* g, u16* l) {
    __builtin_amdgcn_global_load_lds(
        (const __attribute__((address_space(1))) void*)g,
        (__attribute__((address_space(3))) void*)l, 16, 0, 0);
}

// ---- in-degree count (int) ----
__global__ void k_deg(const int* __restrict__ dst, int* __restrict__ deg) {
    int e = blockIdx.x * blockDim.x + threadIdx.x;
    if (e < N_EDGES) atomicAdd(&deg[dst[e]], 1);
}

// ---- local scan + dinv fused ----
__global__ void k_scan_local(const int* __restrict__ deg, int* __restrict__ rowptr,
                             int* __restrict__ bsum, float* __restrict__ dinv) {
    __shared__ int s[256];
    int tid = threadIdx.x;
    int i = blockIdx.x * 256 + tid;
    int v = (i < N_NODES) ? deg[i] : 0;
    if (i < N_NODES) dinv[i] = rsqrtf((float)v + 1.0f);
    s[tid] = v;
    __syncthreads();
    #pragma unroll
    for (int off = 1; off < 256; off <<= 1) {
        int t = 0;
        if (tid >= off) t = s[tid - off];
        __syncthreads();
        if (tid >= off) s[tid] += t;
        __syncthreads();
    }
    if (i < N_NODES) rowptr[i] = s[tid] - v;          // exclusive
    if (tid == 255) bsum[blockIdx.x] = s[255];        // block total
}

__global__ void k_scan_bsum(int* __restrict__ bsum, int* __restrict__ boff) {
    __shared__ int s[512];
    int tid = threadIdx.x;
    int v = (tid < SCAN_B) ? bsum[tid] : 0;
    s[tid] = v;
    __syncthreads();
    #pragma unroll
    for (int off = 1; off < 512; off <<= 1) {
        int t = 0;
        if (tid >= off) t = s[tid - off];
        __syncthreads();
        if (tid >= off) s[tid] += t;
        __syncthreads();
    }
    if (tid < SCAN_B) boff[tid] = s[tid] - v;         // exclusive
}

__global__ void k_scan_add(int* __restrict__ rowptr, const int* __restrict__ boff) {
    int i = blockIdx.x * 256 + threadIdx.x;
    if (i < N_NODES) rowptr[i] += boff[blockIdx.x];
    if (i == 0) rowptr[N_NODES] = N_EDGES;
}

// ---- CSR fill + Xs = dinv.*x pad/scale, merged ----
__global__ __launch_bounds__(256) void k_fill_pad(const int* __restrict__ src,
                       const int* __restrict__ dst,
                       const int* __restrict__ rowptr, int* __restrict__ fill,
                       int* __restrict__ col,
                       const float* __restrict__ x, const float* __restrict__ dinv,
                       u16* __restrict__ xs) {
    if (blockIdx.x < FILL_B) {
        int e = blockIdx.x * 256 + threadIdx.x;
        if (e < N_EDGES) {
            int d = dst[e];
            int pos = rowptr[d] + atomicAdd(&fill[d], 1);
            col[pos] = src[e];
        }
    } else {
        int node = (blockIdx.x - FILL_B) * 4 + (threadIdx.x >> 6);
        if (node >= N_NODES) return;
        int lane = threadIdx.x & 63;
        if (lane >= 48) return;
        int d0 = lane * 2, d1 = lane * 2 + 1;
        float dv = dinv[node];
        const float* xr = x + (size_t)node * IN_DIM;
        float v0 = (d0 < IN_DIM) ? xr[d0] * dv : 0.0f;
        float v1 = (d1 < IN_DIM) ? xr[d1] * dv : 0.0f;
        u32 o = (u32)f2b(v0) | ((u32)f2b(v1) << 16);
        *(u32*)(xs + (size_t)node * KPX + d0) = o;
    }
}

// ---- merged prep: W1/W2/W3 transpose->bf16, W4@Wl fold, gptr search ----
__global__ void k_prep(const float* __restrict__ W1, const float* __restrict__ W2,
                       const float* __restrict__ W3, const float* __restrict__ W4,
                       const float* __restrict__ Wl, const float* __restrict__ b4,
                       const float* __restrict__ bl, const int* __restrict__ batch,
                       u16* __restrict__ Wt1, u16* __restrict__ Wt2, u16* __restrict__ Wt3,
                       float* __restrict__ W4l, float* __restrict__ c4, int* __restrict__ gptr) {
    int b = blockIdx.x;
    int t = threadIdx.x;
    if (b < KPA) {                       // Wt1 [256 x 128], zero-padded K
        Wt1[(size_t)t * KPA + b] = (b < IN_DIM) ? f2b(W1[(size_t)b * HID + t]) : (u16)0;
    } else if (b < KPA + HID) {          // Wt2 [256 x 256]
        int k = b - KPA;
        Wt2[(size_t)t * HID + k] = f2b(W2[(size_t)k * HID + t]);
    } else if (b < KPA + 2 * HID) {      // Wt3
        int k = b - KPA - HID;
        Wt3[(size_t)t * HID + k] = f2b(W3[(size_t)k * HID + t]);
    } else if (b == KPA + 2 * HID) {     // W4l = W4 @ Wl ; c4 = b4 @ Wl + bl
        float s0 = 0.0f, s1 = 0.0f;
        const float* wr = W4 + (size_t)t * HID;
        for (int j = 0; j < HID; ++j) {
            float w = wr[j];
            s0 += w * Wl[j * 2 + 0];
            s1 += w * Wl[j * 2 + 1];
        }
        W4l[t * 2 + 0] = s0;
        W4l[t * 2 + 1] = s1;
        if (t < 2) {
            float s = bl[t];
            for (int j = 0; j < HID; ++j) s += b4[j] * Wl[j * 2 + t];
            c4[t] = s;
        }
    } else {                             // gptr: lower_bound(batch, g)
        int g = (b - (KPA + 2 * HID + 1)) * 256 + t;
        if (g > NG) return;
        if (g == NG) { gptr[NG] = N_NODES; return; }
        int lo = 0, hi = N_NODES;
        while (lo < hi) {
            int mid = (lo + hi) >> 1;
            if (batch[mid] < g) lo = mid + 1; else hi = mid;
        }
        gptr[g] = lo;
    }
}

// ---- 96-dim aggregate -> Xa [M_PAD x 128]; 32 lanes/node, predicated unroll-8 ----
__global__ __launch_bounds__(256) void k_agg96(const int* __restrict__ rowptr,
                                               const int* __restrict__ col,
                                               const u16* __restrict__ xs,
                                               const float* __restrict__ dinv,
                                               u16* __restrict__ xa) {
    int node = blockIdx.x * 8 + (threadIdx.x >> 5);
    if (node >= N_NODES) return;
    int l = threadIdx.x & 31;
    int j = l * 4;
    if (l >= 24) {                       // K-pad region (dims 96..127) -> zero
        *(uint2*)(xa + (size_t)node * KPA + j) = make_uint2(0, 0);
        return;
    }
    const u16* xj = xs + j;
    float a[4];
    {
        uint2 v = *(const uint2*)(xj + (size_t)node * KPX);
        a[0] = lo16(v.x); a[1] = hi16(v.x); a[2] = lo16(v.y); a[3] = hi16(v.y);
    }
    int e = rowptr[node], end = rowptr[node + 1];
    for (; e < end; e += 8) {
        int idx[8]; float mm[8];
        #pragma unroll
        for (int u = 0; u < 8; ++u) {
            int ee = e + u;
            idx[u] = (ee < end) ? ee : e;
            mm[u]  = (ee < end) ? 1.0f : 0.0f;
        }
        mm[0] = 1.0f;
        uint2 w[8];
        #pragma unroll
        for (int u = 0; u < 8; ++u) w[u] = *(const uint2*)(xj + (size_t)col[idx[u]] * KPX);
        #pragma unroll
        for (int u = 0; u < 8; ++u) acc4(a, w[u], mm[u]);
    }
    float dv = dinv[node];
    uint2 o;
    o.x = (u32)f2b(a[0] * dv) | ((u32)f2b(a[1] * dv) << 16);
    o.y = (u32)f2b(a[2] * dv) | ((u32)f2b(a[3] * dv) << 16);
    *(uint2*)(xa + (size_t)node * KPA + j) = o;
}

// ---- 128x128-tile MFMA GEMM, global_load_lds staging, XOR-swizzled LDS ----
// MODE 0: Out = dinv[m]*(A@Wt^T).  MODE 1: Out = relu(A@Wt^T + bias).
template<int MODE>
__global__ __launch_bounds__(256) void k_gemm(const u16* __restrict__ A, int KP,
                                              const u16* __restrict__ Wt,
                                              const float* __restrict__ dinv,
                                              const float* __restrict__ bias,
                                              u16* __restrict__ Out) {
    __shared__ __align__(16) u16 As[128 * 64];   // [row][chunk ^ (row&7)]
    __shared__ __align__(16) u16 Bs[128 * 64];

    const int tid  = threadIdx.x;
    const int wave = tid >> 6;
    const int lane = tid & 63;
    const int quad = lane >> 4;
    const int lm   = lane & 15;
    const int wr   = wave >> 1;
    const int wc   = wave & 1;
    const int m0   = blockIdx.x * 128;
    const int n0   = blockIdx.y * 128;

    f32x4 acc[4][4] = {};

    const int sr = lane >> 3;
    const int sc = lane & 7;
    const int gc = sc ^ (sr & 7);

    for (int kt = 0; kt < KP; kt += 64) {
        __syncthreads();
        #pragma unroll
        for (int i = 0; i < 4; ++i) {
            int s = wave * 4 + i;
            int r = s * 8 + sr;
            const u16* ga = A  + (size_t)(m0 + r) * KP + kt + gc * 8;
            const u16* gb = Wt + (size_t)(n0 + r) * KP + kt + gc * 8;
            gl_lds16(ga, As + s * 512);
            gl_lds16(gb, Bs + s * 512);
        }
        __syncthreads();

        #pragma unroll
        for (int st = 0; st < 2; ++st) {
            bf16x8 af[4], bfr[4];
            const int slot = ((st * 4 + quad) ^ (lm & 7)) * 8;
            #pragma unroll
            for (int rt = 0; rt < 4; ++rt)
                af[rt] = *(const bf16x8*)(As + (wr * 64 + rt * 16 + lm) * 64 + slot);
            #pragma unroll
            for (int ct = 0; ct < 4; ++ct)
                bfr[ct] = *(const bf16x8*)(Bs + (wc * 64 + ct * 16 + lm) * 64 + slot);
            #pragma unroll
            for (int rt = 0; rt < 4; ++rt)
                #pragma unroll
                for (int ct = 0; ct < 4; ++ct)
                    acc[rt][ct] = __builtin_amdgcn_mfma_f32_16x16x32_bf16(af[rt], bfr[ct], acc[rt][ct], 0, 0, 0);
        }
    }

    #pragma unroll
    for (int rt = 0; rt < 4; ++rt) {
        #pragma unroll
        for (int reg = 0; reg < 4; ++reg) {
            int m = m0 + wr * 64 + rt * 16 + quad * 4 + reg;
            if (m >= N_NODES) continue;
            float dv = (MODE == 0) ? dinv[m] : 0.0f;
            #pragma unroll
            for (int ct = 0; ct < 4; ++ct) {
                int n = n0 + wc * 64 + ct * 16 + lm;
                float v = acc[rt][ct][reg];
                if (MODE == 0) v *= dv;
                else           v = fmaxf(v + bias[n], 0.0f);
                Out[(size_t)m * HID + n] = f2b(v);
            }
        }
    }
}

// ---- 256-dim aggregate + bias + relu; 32 lanes/node, 16B loads, predicated unroll-8 ----
__global__ __launch_bounds__(256) void k_agg256(const int* __restrict__ rowptr,
                                                const int* __restrict__ col,
                                                const u16* __restrict__ g,
                                                const float* __restrict__ dinv,
                                                const float* __restrict__ bias,
                                                u16* __restrict__ Xout) {
    int node = blockIdx.x * 8 + (threadIdx.x >> 5);
    if (node >= N_NODES) return;
    int l = threadIdx.x & 31;
    int j = l * 8;
    const u16* gj = g + j;

    float a[8];
    {
        uint4 v = *(const uint4*)(gj + (size_t)node * HID);
        a[0] = lo16(v.x); a[1] = hi16(v.x); a[2] = lo16(v.y); a[3] = hi16(v.y);
        a[4] = lo16(v.z); a[5] = hi16(v.z); a[6] = lo16(v.w); a[7] = hi16(v.w);
    }
    int e = rowptr[node], end = rowptr[node + 1];
    for (; e < end; e += 8) {
        int idx[8]; float mm[8];
        #pragma unroll
        for (int u = 0; u < 8; ++u) {
            int ee = e + u;
            idx[u] = (ee < end) ? ee : e;
            mm[u]  = (ee < end) ? 1.0f : 0.0f;
        }
        mm[0] = 1.0f;
        uint4 w[8];
        #pragma unroll
        for (int u = 0; u < 8; ++u) w[u] = *(const uint4*)(gj + (size_t)col[idx[u]] * HID);
        #pragma unroll
        for (int u = 0; u < 8; ++u) acc8(a, w[u], mm[u]);
    }
    float dv = dinv[node];
    float4 b0 = *(const float4*)(bias + j);
    float4 b1 = *(const float4*)(bias + j + 4);
    float r0 = fmaxf(fmaf(a[0], dv, b0.x), 0.0f);
    float r1 = fmaxf(fmaf(a[1], dv, b0.y), 0.0f);
    float r2 = fmaxf(fmaf(a[2], dv, b0.z), 0.0f);
    float r3 = fmaxf(fmaf(a[3], dv, b0.w), 0.0f);
    float r4 = fmaxf(fmaf(a[4], dv, b1.x), 0.0f);
    float r5 = fmaxf(fmaf(a[5], dv, b1.y), 0.0f);
    float r6 = fmaxf(fmaf(a[6], dv, b1.z), 0.0f);
    float r7 = fmaxf(fmaf(a[7], dv, b1.w), 0.0f);
    uint4 o;
    o.x = (u32)f2b(r0) | ((u32)f2b(r1) << 16);
    o.y = (u32)f2b(r2) | ((u32)f2b(r3) << 16);
    o.z = (u32)f2b(r4) | ((u32)f2b(r5) << 16);
    o.w = (u32)f2b(r6) | ((u32)f2b(r7) << 16);
    *(uint4*)(Xout + (size_t)node * HID + j) = o;
}

// ---- fused layer-3 agg + relu + W4l projection -> g4 [N x 2] f32 ----
// 32 lanes/node; gather g3, X4 = relu(dinv*sum + b3) in regs, dot with W4l (LDS),
// width-32 shuffle reduce, scale by dinv (layer-4 g normalization).
__global__ __launch_bounds__(256) void k_agg_head(const int* __restrict__ rowptr,
                                                  const int* __restrict__ col,
                                                  const u16* __restrict__ g,
                                                  const float* __restrict__ dinv,
                                                  const float* __restrict__ bias,
                                                  const float* __restrict__ W4l,
                                                  float* __restrict__ g4) {
    __shared__ float2 sW[HID];
    sW[threadIdx.x] = *(const float2*)(W4l + threadIdx.x * 2);
    __syncthreads();

    int node = blockIdx.x * 8 + (threadIdx.x >> 5);
    if (node >= N_NODES) return;
    int l = threadIdx.x & 31;
    int j = l * 8;
    const u16* gj = g + j;

    float a[8];
    {
        uint4 v = *(const uint4*)(gj + (size_t)node * HID);
        a[0] = lo16(v.x); a[1] = hi16(v.x); a[2] = lo16(v.y); a[3] = hi16(v.y);
        a[4] = lo16(v.z); a[5] = hi16(v.z); a[6] = lo16(v.w); a[7] = hi16(v.w);
    }
    int e = rowptr[node], end = rowptr[node + 1];
    for (; e < end; e += 8) {
        int idx[8]; float mm[8];
        #pragma unroll
        for (int u = 0; u < 8; ++u) {
            int ee = e + u;
            idx[u] = (ee < end) ? ee : e;
            mm[u]  = (ee < end) ? 1.0f : 0.0f;
        }
        mm[0] = 1.0f;
        uint4 w[8];
        #pragma unroll
        for (int u = 0; u < 8; ++u) w[u] = *(const uint4*)(gj + (size_t)col[idx[u]] * HID);
        #pragma unroll
        for (int u = 0; u < 8; ++u) acc8(a, w[u], mm[u]);
    }
    float dv = dinv[node];
    float4 b0 = *(const float4*)(bias + j);
    float4 b1 = *(const float4*)(bias + j + 4);
    float r[8];
    r[0] = fmaxf(fmaf(a[0], dv, b0.x), 0.0f);
    r[1] = fmaxf(fmaf(a[1], dv, b0.y), 0.0f);
    r[2] = fmaxf(fmaf(a[2], dv, b0.z), 0.0f);
    r[3] = fmaxf(fmaf(a[3], dv, b0.w), 0.0f);
    r[4] = fmaxf(fmaf(a[4], dv, b1.x), 0.0f);
    r[5] = fmaxf(fmaf(a[5], dv, b1.y), 0.0f);
    r[6] = fmaxf(fmaf(a[6], dv, b1.z), 0.0f);
    r[7] = fmaxf(fmaf(a[7], dv, b1.w), 0.0f);
    float s0 = 0.0f, s1 = 0.0f;
    #pragma unroll
    for (int i = 0; i < 8; ++i) {
        float2 w = sW[j + i];
        s0 = fmaf(r[i], w.x, s0);
        s1 = fmaf(r[i], w.y, s1);
    }
    #pragma unroll
    for (int off = 16; off >= 1; off >>= 1) {
        s0 += __shfl_down(s0, off, 32);
        s1 += __shfl_down(s1, off, 32);
    }
    if (l == 0)
        *(float2*)(g4 + (size_t)node * 2) = make_float2(s0 * dv, s1 * dv);
}

// ---- 2-dim aggregate ----
__global__ void k_agg2(const int* __restrict__ rowptr, const int* __restrict__ col,
                       const float* __restrict__ g4, const float* __restrict__ dinv,
                       float* __restrict__ h4) {
    int node = blockIdx.x * blockDim.x + threadIdx.x;
    if (node >= N_NODES) return;
    float2 a = *(const float2*)(g4 + (size_t)node * 2);
    int e = rowptr[node], end = rowptr[node + 1];
    for (; e < end; ++e) {
        float2 w = *(const float2*)(g4 + (size_t)col[e] * 2);
        a.x += w.x; a.y += w.y;
    }
    float dv = dinv[node];
    *(float2*)(h4 + (size_t)node * 2) = make_float2(a.x * dv, a.y * dv);
}

// ---- per-graph mean of h4 + c4 -> out [NG x 2] f32 ----
__global__ __launch_bounds__(256) void k_pool2(const float* __restrict__ h4,
                                               const int* __restrict__ gptr,
                                               const float* __restrict__ c4,
                                               float* __restrict__ out) {
    int gph = blockIdx.x * 4 + (threadIdx.x >> 6);
    if (gph >= NG) return;
    int lane = threadIdx.x & 63;
    int b = gptr[gph], e = gptr[gph + 1];
    float s0 = 0.0f, s1 = 0.0f;
    for (int n = b + lane; n < e; n += 64) {
        float2 v = *(const float2*)(h4 + (size_t)n * 2);
        s0 += v.x; s1 += v.y;
    }
    #pragma unroll
    for (int off = 32; off >= 1; off >>= 1) {
        s0 += __shfl_down(s0, off);
        s1 += __shfl_down(s1, off);
    }
    if (lane == 0) {
        float inv = 1.0f / fmaxf((float)(e - b), 1.0f);
        out[gph * 2 + 0] = s0 * inv + c4[0];
        out[gph * 2 + 1] = s1 * inv + c4[1];
    }
}

extern "C" void kernel_launch(void* const* d_in, const int* in_sizes, int n_in,
                              void* d_out, int out_size, void* d_ws, size_t ws_size,
                              hipStream_t stream) {
    const float* x   = (const float*)d_in[0];
    const int* ei    = (const int*)d_in[1];
    const int* src   = ei;
    const int* dst   = ei + N_EDGES;
    const int* batch = (const int*)d_in[2];
    const float* W1 = (const float*)d_in[3];  const float* b1 = (const float*)d_in[4];
    const float* W2 = (const float*)d_in[5];  const float* b2 = (const float*)d_in[6];
    const float* W3 = (const float*)d_in[7];  const float* b3 = (const float*)d_in[8];
    const float* W4 = (const float*)d_in[9];  const float* b4 = (const float*)d_in[10];
    const float* Wl = (const float*)d_in[11]; const float* bl = (const float*)d_in[12];
    float* out = (float*)d_out;

    // ---- workspace layout ----
    char* p = (char*)d_ws;
    auto take = [&](size_t bytes) { char* r = p; p += (bytes + 255) & ~(size_t)255; return r; };
    size_t zbytes = (size_t)(N_NODES + N_NODES) * 4;   // deg | fill
    int*   deg  = (int*)take(zbytes);
    int*   fill = deg + N_NODES;
    float* dinv = (float*)take((size_t)N_NODES * sizeof(float));
    int* rowptr = (int*)take((size_t)(N_NODES + 1) * sizeof(int));
    int* col    = (int*)take((size_t)N_EDGES * sizeof(int));
    int* bsum   = (int*)take((size_t)SCAN_B * sizeof(int));
    int* boff   = (int*)take((size_t)SCAN_B * sizeof(int));
    int* gptr   = (int*)take((size_t)(NG + 1) * sizeof(int));
    float* W4l  = (float*)take((size_t)HID * 2 * sizeof(float));
    float* c4   = (float*)take(2 * sizeof(float));
    float* g4   = (float*)take((size_t)N_NODES * 2 * sizeof(float));
    float* h4   = (float*)take((size_t)N_NODES * 2 * sizeof(float));
    u16* Wt1 = (u16*)take((size_t)HID * KPA * 2);
    u16* Wt2 = (u16*)take((size_t)HID * HID * 2);
    u16* Wt3 = (u16*)take((size_t)HID * HID * 2);
    u16* Xs  = (u16*)take((size_t)N_NODES * KPX * 2);
    u16* Xa  = (u16*)take((size_t)M_PAD * KPA * 2);    // padded rows for 128-tile staging
    u16* Gbuf = (u16*)take((size_t)N_NODES * HID * 2);
    u16* Xbuf = (u16*)take((size_t)M_PAD * HID * 2);   // padded rows for 128-tile staging

    hipMemsetAsync(deg, 0, zbytes, stream);

    // CSR build + norms + prep
    k_deg<<<(N_EDGES + 255) / 256, 256, 0, stream>>>(dst, deg);
    k_scan_local<<<SCAN_B, 256, 0, stream>>>(deg, rowptr, bsum, dinv);
    k_scan_bsum<<<1, 512, 0, stream>>>(bsum, boff);
    k_scan_add<<<SCAN_B, 256, 0, stream>>>(rowptr, boff);
    k_fill_pad<<<FILL_B + (N_NODES + 3) / 4, 256, 0, stream>>>(src, dst, rowptr, fill, col,
                                                               x, dinv, Xs);
    k_prep<<<KPA + 2 * HID + 1 + (NG + 256) / 256, 256, 0, stream>>>(
        W1, W2, W3, W4, Wl, b4, bl, batch, Wt1, Wt2, Wt3, W4l, c4, gptr);

    const int nb8 = (N_NODES + 7) / 8;
    const dim3 gemm_grid(M_PAD / 128, HID / 128);

    // layer 1: aggregate-first in input space, bias+relu fused in GEMM
    k_agg96<<<nb8, 256, 0, stream>>>(rowptr, col, Xs, dinv, Xa);
    k_gemm<1><<<gemm_grid, 256, 0, stream>>>(Xa, KPA, Wt1, dinv, b1, Xbuf);
    // layer 2
    k_gemm<0><<<gemm_grid, 256, 0, stream>>>(Xbuf, HID, Wt2, dinv, b2, Gbuf);
    k_agg256<<<nb8, 256, 0, stream>>>(rowptr, col, Gbuf, dinv, b2, Xbuf);
    // layer 3 GEMM -> g3; then fused agg+relu+head projection -> g4
    k_gemm<0><<<gemm_grid, 256, 0, stream>>>(Xbuf, HID, Wt3, dinv, b3, Gbuf);
    k_agg_head<<<nb8, 256, 0, stream>>>(rowptr, col, Gbuf, dinv, b3, W4l, g4);
    // layer 4 + head tail
    k_agg2<<<(N_NODES + 255) / 256, 256, 0, stream>>>(rowptr, col, g4, dinv, h4);
    k_pool2<<<(NG + 3) / 4, 256, 0, stream>>>(h4, gptr, c4, out);
}